// Round 2
// baseline (1396.471 us; speedup 1.0000x reference)
//
#include <hip/hip_runtime.h>
#include <hip/hip_bf16.h>

// Problem constants (AKT core): B=16, S=512, D=512, H=8, DFF=2048, NB=2, L=6
#define Bsz  16
#define Sl   512
#define Dm   512
#define Hn   8
#define DKh  64
#define DFFn 2048
#define MROWS (Bsz * Sl)      // 8192
#define NEGV (-1e32f)

typedef _Float16 f16;
typedef f16 f16x8 __attribute__((ext_vector_type(8)));
typedef f16 f16x4 __attribute__((ext_vector_type(4)));
typedef float f32x4 __attribute__((ext_vector_type(4)));

// async global->LDS, 16B per lane: lds dst = wave-uniform base + lane*16
#define GLDS16(g, l) __builtin_amdgcn_global_load_lds( \
    (const __attribute__((address_space(1))) void*)(g), \
    (__attribute__((address_space(3))) void*)(l), 16, 0, 0)

// ---------------------------------------------------------------------------
// copies
// ---------------------------------------------------------------------------
__global__ void k_copy2(const float* __restrict__ in, float* __restrict__ out,
                        f16* __restrict__ outh, int n) {
    int i = blockIdx.x * 256 + threadIdx.x;
    if (i < n) { float v = in[i]; out[i] = v; outh[i] = (f16)v; }
}

// ---------------------------------------------------------------------------
// Weight convert+transpose: W[K,N] f32 -> Wt[N,K] f16 (per layer slice z).
// lmap=1 maps output slot z -> source layer {0,1,3,5}.
// ---------------------------------------------------------------------------
__global__ __launch_bounds__(256) void k_wconv(const float* __restrict__ src,
        f16* __restrict__ dst, int K, int N, int lmap)
{
    __shared__ float T[32][36];
    int z = blockIdx.z;
    int ls = lmap ? (z < 2 ? z : 2 * z - 1) : z;
    const float* S = src + (size_t)ls * K * N;
    f16* Dt = dst + (size_t)z * K * N;
    int n0 = blockIdx.x * 32, k0 = blockIdx.y * 32;
    int t = threadIdx.x;
    int r = t >> 3, c = (t & 7) * 4;
    float4 v = *(const float4*)(S + (size_t)(k0 + r) * N + n0 + c);
    T[r][c] = v.x; T[r][c + 1] = v.y; T[r][c + 2] = v.z; T[r][c + 3] = v.w;
    __syncthreads();
    int n = t >> 3, kq = (t & 7) * 4;
    f16x4 o = { (f16)T[kq][n], (f16)T[kq + 1][n], (f16)T[kq + 2][n], (f16)T[kq + 3][n] };
    *(f16x4*)(Dt + (size_t)(n0 + n) * K + k0 + kq) = o;
}

// ---------------------------------------------------------------------------
// MFMA f16 GEMM: C[M,N] = A[M,K] @ Bt[N,K]^T + bias[N]. A,Bt f16; bias f32.
// 128x128 tile, BK=32, 4 waves (2x2 of 64x64), 16x16x32 MFMA, 4x4 tiles/wave.
// 2-phase pipeline: LDS double-buffer, stage(t+1) issued BEFORE compute(t),
// single __syncthreads() (vmcnt drain) per K-step.
// VTOUT=1: write V-projection output directly in vt[bh][d][s] f16 layout.
// ---------------------------------------------------------------------------
template <int RELU, int OUT16, int VTOUT>
__global__ __launch_bounds__(256) void k_gemm(
    const f16* __restrict__ A, const f16* __restrict__ Bt,
    const float* __restrict__ bias, float* __restrict__ C, f16* __restrict__ Ch,
    int M, int N, int K)
{
    __shared__ f16 As[2 * 128 * 32];
    __shared__ f16 Bs[2 * 128 * 32];
    int tid = threadIdx.x;
    int w = tid >> 6, lane = tid & 63;
    int ln = lane & 15, rg = lane >> 4;
    int wr = w >> 1, wc = w & 1;
    int m0 = blockIdx.y * 128, n0 = blockIdx.x * 128;

    int s0 = tid, s1 = 256 + tid;
    int r0s = s0 >> 2, c0s = ((s0 & 3) ^ ((s0 >> 3) & 3));
    int r1s = s1 >> 2, c1s = ((s1 & 3) ^ ((s1 >> 3) & 3));

    const f16* a0 = A + (size_t)(m0 + r0s) * K + c0s * 8;
    const f16* a1 = A + (size_t)(m0 + r1s) * K + c1s * 8;
    const f16* b0 = Bt + (size_t)(n0 + r0s) * K + c0s * 8;
    const f16* b1 = Bt + (size_t)(n0 + r1s) * K + c1s * 8;

    int cc8 = (rg ^ ((ln >> 1) & 3)) * 8;

    f32x4 acc[4][4] = {};

    int nk = K >> 5;

    // prologue: stage K-step 0 into buffer 0
    {
        f16* lA = As + (size_t)(w * 64) * 8;
        f16* lB = Bs + (size_t)(w * 64) * 8;
        GLDS16(a0, lA);
        GLDS16(a1, lA + 2048);
        GLDS16(b0, lB);
        GLDS16(b1, lB + 2048);
    }
    __syncthreads();   // vmcnt(0) drain: buf0 ready

    int cur = 0;
    for (int t = 0; t < nk; ++t) {
        // issue next-tile loads FIRST (overlap with compute below)
        if (t + 1 < nk) {
            int kt = (t + 1) << 5;
            int nb = cur ^ 1;
            f16* lA = As + nb * 4096 + (size_t)(w * 64) * 8;
            f16* lB = Bs + nb * 4096 + (size_t)(w * 64) * 8;
            GLDS16(a0 + kt, lA);
            GLDS16(a1 + kt, lA + 2048);
            GLDS16(b0 + kt, lB);
            GLDS16(b1 + kt, lB + 2048);
        }

        const f16* Ab = As + cur * 4096;
        const f16* Bb = Bs + cur * 4096;
        f16x8 af[4], bf[4];
#pragma unroll
        for (int i = 0; i < 4; ++i) {
            int m = wr * 64 + i * 16 + ln;
            af[i] = *(const f16x8*)(Ab + m * 32 + cc8);
            int nn = wc * 64 + i * 16 + ln;
            bf[i] = *(const f16x8*)(Bb + nn * 32 + cc8);
        }
#pragma unroll
        for (int i = 0; i < 4; ++i)
#pragma unroll
            for (int j = 0; j < 4; ++j)
                acc[i][j] = __builtin_amdgcn_mfma_f32_16x16x32_f16(af[i], bf[j], acc[i][j], 0, 0, 0);

        __syncthreads();   // drains vmcnt(0): next buffer staged, reads done
        cur ^= 1;
    }

#pragma unroll
    for (int j = 0; j < 4; ++j) {
        int col = n0 + wc * 64 + j * 16 + ln;
        float bj = bias[col];
#pragma unroll
        for (int i = 0; i < 4; ++i) {
            int rb = m0 + wr * 64 + i * 16 + rg * 4;
            if (VTOUT) {
                // vt[((b*8+h)*64 + dk)*512 + s], s = 4 consecutive rows
                int bq = rb >> 9, s = rb & 511;
                int hh = col >> 6, dk = col & 63;
                f16x4 o;
#pragma unroll
                for (int r = 0; r < 4; ++r) o[r] = (f16)(acc[i][j][r] + bj);
                *(f16x4*)(Ch + (((size_t)(bq * 8 + hh) * 64 + dk) << 9) + s) = o;
            } else {
#pragma unroll
                for (int r = 0; r < 4; ++r) {
                    float v = acc[i][j][r] + bj;
                    if (RELU) v = fmaxf(v, 0.f);
                    if (OUT16) Ch[(size_t)(rb + r) * N + col] = (f16)v;
                    else       C [(size_t)(rb + r) * N + col] = v;
                }
            }
        }
    }
}

// ---------------------------------------------------------------------------
// AKT attention, MFMA. One block per (b, h, 16-row i-tile), 4 waves.
// Phase 1: S = Q K^T via mfma (frags from global), C-frags -> LDS Sc f32.
// Phase 2: jtc-scaled softmax/cumsum/decay/softmax. Each lane owns jtc
//          contiguous cols (j = lane*jtc + k) so work scales with the
//          causal extent instead of always covering 512 cols. First
//          softmax is shift-free (|s|<~20) and its Z comes from the scan
//          (lane 63) -> only 3 chained shuffle reductions per row.
//          Ph (f16 P-matrix) ALIASES Sc: waves pre-read their 4 rows into
//          regs, barrier, then compute+write. LDS 32KB -> 4-5 blocks/CU.
// Phase 3: O = P V via mfma; wave w owns d-block; B from vt global.
// ---------------------------------------------------------------------------
__global__ __launch_bounds__(256, 4) void k_attn(
    const f16* __restrict__ Qh, const f16* __restrict__ VT,
    f16* __restrict__ O, const float* __restrict__ gam, int maskflag)
{
    __shared__ float Sc[16][512];
    f16* Ph = (f16*)Sc;          // 16KB alias, safe after pre-read barrier

    int tid = threadIdx.x;
    int w = tid >> 6, lane = tid & 63;
    int ln = lane & 15, rg = lane >> 4;
    int tile = blockIdx.x & 31;
    int bh = blockIdx.x >> 5;
    int b = bh >> 3, h = bh & 7;
    int i0 = tile * 16;
    int jtc = (tile >> 2) + 1;          // valid j-tiles (64 cols each)

    const f16* Qbase = Qh + ((size_t)b * Sl) * Dm + h * DKh;

    float gm = gam[h];
    float g = -((gm > 20.f) ? gm : log1pf(__expf(gm)));   // -softplus(gamma)

    // A-frags: Q rows i0..i0+15, reused across j-tiles
    f16x8 aq0 = *(const f16x8*)(Qbase + (size_t)(i0 + ln) * Dm + rg * 8);
    f16x8 aq1 = *(const f16x8*)(Qbase + (size_t)(i0 + ln) * Dm + 32 + rg * 8);

    // ---- Phase 1: scores ------------------------------------------------
    for (int jt = w; jt < jtc; jt += 4) {
        int j0 = jt * 64;
#pragma unroll
        for (int nb = 0; nb < 4; ++nb) {
            const f16* kb = Qbase + (size_t)(j0 + nb * 16 + ln) * Dm + rg * 8;
            f16x8 b0 = *(const f16x8*)(kb);
            f16x8 b1 = *(const f16x8*)(kb + 32);
            f32x4 c = {};
            c = __builtin_amdgcn_mfma_f32_16x16x32_f16(aq0, b0, c, 0, 0, 0);
            c = __builtin_amdgcn_mfma_f32_16x16x32_f16(aq1, b1, c, 0, 0, 0);
#pragma unroll
            for (int r = 0; r < 4; ++r)
                Sc[rg * 4 + r][j0 + nb * 16 + ln] = c[r];
        }
    }
    __syncthreads();

    // ---- Phase 2a: pre-read this wave's 4 rows (before Ph overwrites Sc)
    int jbase = lane * jtc;
    float s4[4][8];
    if (jtc == 8) {
#pragma unroll
        for (int q = 0; q < 4; ++q) {
            int r = w * 4 + q;
            float4 t0 = *(float4*)&Sc[r][jbase];
            float4 t1 = *(float4*)&Sc[r][jbase + 4];
            s4[q][0] = t0.x; s4[q][1] = t0.y; s4[q][2] = t0.z; s4[q][3] = t0.w;
            s4[q][4] = t1.x; s4[q][5] = t1.y; s4[q][6] = t1.z; s4[q][7] = t1.w;
        }
    } else {
#pragma unroll
        for (int q = 0; q < 4; ++q) {
            int r = w * 4 + q;
#pragma unroll
            for (int k = 0; k < 8; ++k)
                if (k < jtc) s4[q][k] = Sc[r][jbase + k];
        }
    }
    __syncthreads();   // all Sc reads done; Ph may now overwrite

    // ---- Phase 2b: softmax -> cumsum -> decay -> softmax ----------------
    for (int q = 0; q < 4; ++q) {
        int r = w * 4 + q;
        int i = i0 + r;
        int jmax = maskflag ? i : (i - 1);

        float sv[8], cs[8], pp[8];
        float run = 0.f;
#pragma unroll
        for (int k = 0; k < 8; ++k) if (k < jtc) {
            int j = jbase + k;
            float s = (j <= jmax) ? s4[q][k] * 0.125f : NEGV;
            sv[k] = s;
            float pe = __expf(s);      // exp(-1e32) = 0 for masked
            run += pe;
            cs[k] = run;               // per-lane inclusive sum
        }
        // inclusive scan across lanes (j-ordered); lane 63's value = Z
        float sl = run;
#pragma unroll
        for (int off = 1; off < 64; off <<= 1) {
            float nv = __shfl_up(sl, off);
            if (lane >= off) sl += nv;
        }
        float excl = sl - run;
        float Z = __shfl(sl, 63);
        float inv = 1.f / Z;

#pragma unroll
        for (int k = 0; k < 8; ++k) if (k < jtc) {
            int j = jbase + k;
            float rem = (Z - excl - cs[k]) * inv;     // disttot - distcum
            float pos = fabsf((float)(i - j));
            float dd = fmaxf(rem * pos, 0.f);         // fmax(NaN,0)=0 safe
            float te = __expf(sqrtf(dd) * g);
            te = fminf(fmaxf(te, 1e-5f), 1e5f);
            sv[k] = (j <= jmax) ? sv[k] * te : NEGV;
        }

        float m = NEGV;
#pragma unroll
        for (int k = 0; k < 8; ++k) if (k < jtc) m = fmaxf(m, sv[k]);
#pragma unroll
        for (int off = 32; off >= 1; off >>= 1) m = fmaxf(m, __shfl_xor(m, off));
        float Z2 = 0.f;
#pragma unroll
        for (int k = 0; k < 8; ++k) if (k < jtc) {
            pp[k] = __expf(sv[k] - m);
            Z2 += pp[k];
        }
#pragma unroll
        for (int off = 32; off >= 1; off >>= 1) Z2 += __shfl_xor(Z2, off);
        float inv2 = 1.f / Z2;

        int zp = (maskflag == 0) && (i == 0);
        // write P f16 into swizzled Ph (chunk cj, slot low3 ^= r&7)
        if (jtc == 8) {
            float a[8];
#pragma unroll
            for (int k = 0; k < 8; ++k) a[k] = zp ? 0.f : pp[k] * inv2;
            int slot = (lane & ~7) | ((lane & 7) ^ (r & 7));
            f16x8 o8 = { (f16)a[0], (f16)a[1], (f16)a[2], (f16)a[3],
                         (f16)a[4], (f16)a[5], (f16)a[6], (f16)a[7] };
            *(f16x8*)(Ph + r * 512 + slot * 8) = o8;
        } else {
#pragma unroll
            for (int k = 0; k < 8; ++k) if (k < jtc) {
                int j = jbase + k;
                int cj = j >> 3;
                int slot = (cj & ~7) | ((cj & 7) ^ (r & 7));
                float a = zp ? 0.f : pp[k] * inv2;
                Ph[r * 512 + slot * 8 + (j & 7)] = (f16)a;
            }
        }
    }
    __syncthreads();

    // ---- Phase 3: O = P @ V, wave w owns d-block nb=w -------------------
    f32x4 oa = {};
    for (int jt = 0; jt < jtc; ++jt) {
        int j0 = jt * 64;
#pragma unroll
        for (int ks = 0; ks < 2; ++ks) {
            int c = jt * 8 + ks * 4 + rg;
            int slot = (c & ~7) | ((c & 7) ^ (ln & 7));
            f16x8 ap = *(const f16x8*)(Ph + ln * 512 + slot * 8);
            const f16* vb_ = VT + ((size_t)bh * 64 + w * 16 + ln) * 512
                             + j0 + ks * 32 + rg * 8;
            f16x8 bv = *(const f16x8*)vb_;
            oa = __builtin_amdgcn_mfma_f32_16x16x32_f16(ap, bv, oa, 0, 0, 0);
        }
    }
    f16* ob = O + ((size_t)b * Sl + i0 + rg * 4) * Dm + h * DKh + w * 16 + ln;
#pragma unroll
    for (int r = 0; r < 4; ++r)
        ob[(size_t)r * Dm] = (f16)oa[r];
}

// ---------------------------------------------------------------------------
// Residual + LayerNorm: Out = LN(Xn + Rr)*g + b, dual f32+f16 output.
// ---------------------------------------------------------------------------
__global__ __launch_bounds__(256) void k_ln(
    const float* __restrict__ Xn, const float* __restrict__ Rr,
    const float* __restrict__ gw, const float* __restrict__ bw,
    float* __restrict__ Out, f16* __restrict__ Outh)
{
    int tid = threadIdx.x;
    int w = tid >> 6, lane = tid & 63;
    int row = blockIdx.x * 4 + w;
    const float* xr = Xn + (size_t)row * Dm;
    const float* rr = Rr + (size_t)row * Dm;
    float v[8], sum = 0.f;
#pragma unroll
    for (int r = 0; r < 8; ++r) {
        int c = lane + r * 64;
        v[r] = xr[c] + rr[c];
        sum += v[r];
    }
#pragma unroll
    for (int off = 32; off >= 1; off >>= 1) sum += __shfl_xor(sum, off);
    float mu = sum * (1.f / 512.f);
    float var = 0.f;
#pragma unroll
    for (int r = 0; r < 8; ++r) { float d = v[r] - mu; var += d * d; }
#pragma unroll
    for (int off = 32; off >= 1; off >>= 1) var += __shfl_xor(var, off);
    float rs = rsqrtf(var * (1.f / 512.f) + 1e-5f);
    float* orow = Out + (size_t)row * Dm;
    f16* ohrow = Outh + (size_t)row * Dm;
#pragma unroll
    for (int r = 0; r < 8; ++r) {
        int c = lane + r * 64;
        float val = (v[r] - mu) * rs * gw[c] + bw[c];
        orow[c] = val;
        ohrow[c] = (f16)val;
    }
}

// ---------------------------------------------------------------------------
extern "C" void kernel_launch(void* const* d_in, const int* in_sizes, int n_in,
                              void* d_out, int out_size, void* d_ws, size_t ws_size,
                              hipStream_t stream)
{
    const float* q_emb  = (const float*)d_in[0];
    const float* qa_emb = (const float*)d_in[1];
    const float* Wk  = (const float*)d_in[3];
    const float* bk  = (const float*)d_in[4];
    const float* Wv  = (const float*)d_in[5];
    const float* bv  = (const float*)d_in[6];
    const float* Wo  = (const float*)d_in[7];
    const float* bo  = (const float*)d_in[8];
    const float* gam = (const float*)d_in[9];
    const float* l1g = (const float*)d_in[10];
    const float* l1b = (const float*)d_in[11];
    const float* W1  = (const float*)d_in[12];
    const float* b1  = (const float*)d_in[13];
    const float* W2  = (const float*)d_in[14];
    const float* b2  = (const float*)d_in[15];
    const float* l2g = (const float*)d_in[16];
    const float* l2b = (const float*)d_in[17];
    float* outp = (float*)d_out;

    const size_t NE  = (size_t)MROWS * Dm;    // 4194304
    const size_t WDD = (size_t)Dm * Dm;
    const size_t WDF = (size_t)Dm * DFFn;

    float* xbuf = (float*)d_ws;               // NE f32
    float* ybuf = xbuf + NE;                  // NE f32
    float* t2   = ybuf + NE;                  // NE f32 (LN input temp)
    f16* xh  = (f16*)(t2 + NE);               // NE
    f16* yh  = xh + NE;                       // NE
    f16* R   = yh + NE;                       // 4*NE f16 region
    f16* qh  = R;                             // q(=k) heads f16
    f16* vt  = R + 2 * NE;                    // v transposed per head (fused)
    f16* t1h = R + 3 * NE;                    // attention output f16
    f16* fbh = R;                             // FFN hidden (aliases R, 4*NE)
    f16* wkh = R + 4 * NE;                    // weights f16
    f16* wvh = wkh + 6 * WDD;
    f16* woh = wvh + 6 * WDD;
    f16* w1h = woh + 6 * WDD;                 // slots 0,1,3,5
    f16* w2h = w1h + 4 * WDF;

    // ---- per-call weight convert+transpose (f32 [K,N] -> f16 [N,K]) ----
    k_wconv<<<dim3(Dm / 32, Dm / 32, 6), 256, 0, stream>>>(Wk, wkh, Dm, Dm, 0);
    k_wconv<<<dim3(Dm / 32, Dm / 32, 6), 256, 0, stream>>>(Wv, wvh, Dm, Dm, 0);
    k_wconv<<<dim3(Dm / 32, Dm / 32, 6), 256, 0, stream>>>(Wo, woh, Dm, Dm, 0);
    k_wconv<<<dim3(DFFn / 32, Dm / 32, 4), 256, 0, stream>>>(W1, w1h, Dm, DFFn, 1);
    k_wconv<<<dim3(Dm / 32, DFFn / 32, 4), 256, 0, stream>>>(W2, w2h, DFFn, Dm, 1);

    const int n = (int)NE;
    k_copy2<<<n / 256, 256, 0, stream>>>(q_emb,  xbuf, xh, n);
    k_copy2<<<n / 256, 256, 0, stream>>>(qa_emb, ybuf, yh, n);

    auto gemm16 = [&](const f16* A, const f16* Bt, const float* bias, f16* C,
                      int M, int N, int K) {
        k_gemm<0, 1, 0><<<dim3(N / 128, M / 128), 256, 0, stream>>>(A, Bt, bias, nullptr, C, M, N, K);
    };
    auto gemm32 = [&](const f16* A, const f16* Bt, const float* bias, float* C,
                      int M, int N, int K) {
        k_gemm<0, 0, 0><<<dim3(N / 128, M / 128), 256, 0, stream>>>(A, Bt, bias, C, nullptr, M, N, K);
    };
    auto gemmvt = [&](const f16* A, const f16* Bt, const float* bias, f16* C) {
        k_gemm<0, 1, 1><<<dim3(Dm / 128, MROWS / 128), 256, 0, stream>>>(A, Bt, bias, nullptr, C, MROWS, Dm, Dm);
    };

    // finalOut: if non-null, the LAST LayerNorm's f32 result goes there
    // (the f32 residual stream is dead afterwards; f16 mirror still written).
    auto layer = [&](int l, int maskflag, float* Xq, f16* Xqh, f16* Xvh,
                     bool apply_pos, float* finalOut) {
        gemm16(Xqh, wkh + (size_t)l * WDD, bk + l * Dm, qh, MROWS, Dm, Dm);
        gemmvt(Xvh, wvh + (size_t)l * WDD, bv + l * Dm, vt);
        k_attn<<<Bsz * Hn * 32, 256, 0, stream>>>(qh, vt, t1h, gam + l * Hn, maskflag);
        gemm32(t1h, woh + (size_t)l * WDD, bo + l * Dm, t2, MROWS, Dm, Dm);
        if (apply_pos) {
            k_ln<<<MROWS / 4, 256, 0, stream>>>(t2, Xq, l1g + l * Dm, l1b + l * Dm, Xq, Xqh);
            int sl = (l < 2) ? l : ((l + 1) >> 1);
            k_gemm<1, 1, 0><<<dim3(DFFn / 128, MROWS / 128), 256, 0, stream>>>(
                Xqh, w1h + (size_t)sl * WDF, b1 + l * DFFn, nullptr, fbh, MROWS, DFFn, Dm);
            k_gemm<0, 0, 0><<<dim3(Dm / 128, MROWS / 128), 256, 0, stream>>>(
                fbh, w2h + (size_t)sl * WDF, b2 + l * Dm, t2, nullptr, MROWS, Dm, DFFn);
            k_ln<<<MROWS / 4, 256, 0, stream>>>(t2, Xq, l2g + l * Dm, l2b + l * Dm,
                                                finalOut ? finalOut : Xq, Xqh);
        } else {
            k_ln<<<MROWS / 4, 256, 0, stream>>>(t2, Xq, l1g + l * Dm, l1b + l * Dm,
                                                finalOut ? finalOut : Xq, Xqh);
        }
    };

    const size_t NEo = NE;
    // blocks_1: self-attn on y, mask=1, FFN. Layer 1 is y's final write -> out+NE.
    layer(0, 1, ybuf, yh, yh, true, nullptr);
    layer(1, 1, ybuf, yh, yh, true, outp + NEo);
    // blocks_2: (mask=1, no FFN) then (mask=0, values=y, FFN), twice.
    // Layer 5 is x's final write -> out.
    layer(2, 1, xbuf, xh, xh, false, nullptr);
    layer(3, 0, xbuf, xh, yh, true, nullptr);
    layer(4, 1, xbuf, xh, xh, false, nullptr);
    layer(5, 0, xbuf, xh, yh, true, outp);
}

// Round 3
// 1385.655 us; speedup vs baseline: 1.0078x; 1.0078x over previous
//
#include <hip/hip_runtime.h>
#include <hip/hip_bf16.h>

// Problem constants (AKT core): B=16, S=512, D=512, H=8, DFF=2048, NB=2, L=6
#define Bsz  16
#define Sl   512
#define Dm   512
#define Hn   8
#define DKh  64
#define DFFn 2048
#define MROWS (Bsz * Sl)      // 8192
#define NEGV (-1e32f)

typedef _Float16 f16;
typedef f16 f16x8 __attribute__((ext_vector_type(8)));
typedef f16 f16x4 __attribute__((ext_vector_type(4)));
typedef float f32x4 __attribute__((ext_vector_type(4)));

// async global->LDS, 16B per lane: lds dst = wave-uniform base + lane*16
#define GLDS16(g, l) __builtin_amdgcn_global_load_lds( \
    (const __attribute__((address_space(1))) void*)(g), \
    (__attribute__((address_space(3))) void*)(l), 16, 0, 0)

// ---------------------------------------------------------------------------
// copies
// ---------------------------------------------------------------------------
__global__ void k_copy2(const float* __restrict__ in, float* __restrict__ out,
                        f16* __restrict__ outh, int n) {
    int i = blockIdx.x * 256 + threadIdx.x;
    if (i < n) { float v = in[i]; out[i] = v; outh[i] = (f16)v; }
}

// ---------------------------------------------------------------------------
// Weight convert+transpose: W[K,N] f32 -> Wt[N,K] f16 (per layer slice z).
// lmap=1 maps output slot z -> source layer {0,1,3,5}.
// ---------------------------------------------------------------------------
__global__ __launch_bounds__(256) void k_wconv(const float* __restrict__ src,
        f16* __restrict__ dst, int K, int N, int lmap)
{
    __shared__ float T[32][36];
    int z = blockIdx.z;
    int ls = lmap ? (z < 2 ? z : 2 * z - 1) : z;
    const float* S = src + (size_t)ls * K * N;
    f16* Dt = dst + (size_t)z * K * N;
    int n0 = blockIdx.x * 32, k0 = blockIdx.y * 32;
    int t = threadIdx.x;
    int r = t >> 3, c = (t & 7) * 4;
    float4 v = *(const float4*)(S + (size_t)(k0 + r) * N + n0 + c);
    T[r][c] = v.x; T[r][c + 1] = v.y; T[r][c + 2] = v.z; T[r][c + 3] = v.w;
    __syncthreads();
    int n = t >> 3, kq = (t & 7) * 4;
    f16x4 o = { (f16)T[kq][n], (f16)T[kq + 1][n], (f16)T[kq + 2][n], (f16)T[kq + 3][n] };
    *(f16x4*)(Dt + (size_t)(n0 + n) * K + k0 + kq) = o;
}

// ---------------------------------------------------------------------------
// MFMA f16 GEMM: C[M,N] = A[M,K] @ Bt[N,K]^T + bias[N]. A,Bt f16; bias f32.
// 128x128 tile, BK=32, 4 waves (2x2 of 64x64), 16x16x32 MFMA, 4x4 tiles/wave.
// 2-phase pipeline: LDS double-buffer, stage(t+1) issued BEFORE compute(t),
// single __syncthreads() (vmcnt drain) per K-step.
// VTOUT=1: write V-projection output directly in vt[bh][d][s] f16 layout.
// ---------------------------------------------------------------------------
template <int RELU, int OUT16, int VTOUT>
__global__ __launch_bounds__(256) void k_gemm(
    const f16* __restrict__ A, const f16* __restrict__ Bt,
    const float* __restrict__ bias, float* __restrict__ C, f16* __restrict__ Ch,
    int M, int N, int K)
{
    __shared__ f16 As[2 * 128 * 32];
    __shared__ f16 Bs[2 * 128 * 32];
    int tid = threadIdx.x;
    int w = tid >> 6, lane = tid & 63;
    int ln = lane & 15, rg = lane >> 4;
    int wr = w >> 1, wc = w & 1;
    int m0 = blockIdx.y * 128, n0 = blockIdx.x * 128;

    int s0 = tid, s1 = 256 + tid;
    int r0s = s0 >> 2, c0s = ((s0 & 3) ^ ((s0 >> 3) & 3));
    int r1s = s1 >> 2, c1s = ((s1 & 3) ^ ((s1 >> 3) & 3));

    const f16* a0 = A + (size_t)(m0 + r0s) * K + c0s * 8;
    const f16* a1 = A + (size_t)(m0 + r1s) * K + c1s * 8;
    const f16* b0 = Bt + (size_t)(n0 + r0s) * K + c0s * 8;
    const f16* b1 = Bt + (size_t)(n0 + r1s) * K + c1s * 8;

    int cc8 = (rg ^ ((ln >> 1) & 3)) * 8;

    f32x4 acc[4][4] = {};

    int nk = K >> 5;

    // prologue: stage K-step 0 into buffer 0
    {
        f16* lA = As + (size_t)(w * 64) * 8;
        f16* lB = Bs + (size_t)(w * 64) * 8;
        GLDS16(a0, lA);
        GLDS16(a1, lA + 2048);
        GLDS16(b0, lB);
        GLDS16(b1, lB + 2048);
    }
    __syncthreads();   // vmcnt(0) drain: buf0 ready

    int cur = 0;
    for (int t = 0; t < nk; ++t) {
        // issue next-tile loads FIRST (overlap with compute below)
        if (t + 1 < nk) {
            int kt = (t + 1) << 5;
            int nb = cur ^ 1;
            f16* lA = As + nb * 4096 + (size_t)(w * 64) * 8;
            f16* lB = Bs + nb * 4096 + (size_t)(w * 64) * 8;
            GLDS16(a0 + kt, lA);
            GLDS16(a1 + kt, lA + 2048);
            GLDS16(b0 + kt, lB);
            GLDS16(b1 + kt, lB + 2048);
        }

        const f16* Ab = As + cur * 4096;
        const f16* Bb = Bs + cur * 4096;
        f16x8 af[4], bf[4];
#pragma unroll
        for (int i = 0; i < 4; ++i) {
            int m = wr * 64 + i * 16 + ln;
            af[i] = *(const f16x8*)(Ab + m * 32 + cc8);
            int nn = wc * 64 + i * 16 + ln;
            bf[i] = *(const f16x8*)(Bb + nn * 32 + cc8);
        }
#pragma unroll
        for (int i = 0; i < 4; ++i)
#pragma unroll
            for (int j = 0; j < 4; ++j)
                acc[i][j] = __builtin_amdgcn_mfma_f32_16x16x32_f16(af[i], bf[j], acc[i][j], 0, 0, 0);

        __syncthreads();   // drains vmcnt(0): next buffer staged, reads done
        cur ^= 1;
    }

#pragma unroll
    for (int j = 0; j < 4; ++j) {
        int col = n0 + wc * 64 + j * 16 + ln;
        float bj = bias[col];
#pragma unroll
        for (int i = 0; i < 4; ++i) {
            int rb = m0 + wr * 64 + i * 16 + rg * 4;
            if (VTOUT) {
                // vt[((b*8+h)*64 + dk)*512 + s], s = 4 consecutive rows
                int bq = rb >> 9, s = rb & 511;
                int hh = col >> 6, dk = col & 63;
                f16x4 o;
#pragma unroll
                for (int r = 0; r < 4; ++r) o[r] = (f16)(acc[i][j][r] + bj);
                *(f16x4*)(Ch + (((size_t)(bq * 8 + hh) * 64 + dk) << 9) + s) = o;
            } else {
#pragma unroll
                for (int r = 0; r < 4; ++r) {
                    float v = acc[i][j][r] + bj;
                    if (RELU) v = fmaxf(v, 0.f);
                    if (OUT16) Ch[(size_t)(rb + r) * N + col] = (f16)v;
                    else       C [(size_t)(rb + r) * N + col] = v;
                }
            }
        }
    }
}

// ---------------------------------------------------------------------------
// AKT attention, MFMA. One block per (b, h, 16-row i-tile), 4 waves.
// Heavy-first: tile = 31 - (bid&31) so big-jtc blocks dispatch first (LPT).
// Phase 1: S = Q K^T via mfma, distributed at 16-col UNIT granularity
//          (unit u covers cols [u*16,u*16+16), wave w takes u=w,w+4,..) so
//          all 4 waves work even when jtc<4 (was: whole 64-col j-tiles
//          round-robin -> 3 idle waves for jtc=1). C-frags -> LDS Sc f32,
//          row stride 516 (2-way bank aliasing = free; 512 was 4-way).
// Phase 2: jtc-scaled softmax/cumsum/decay/softmax; lane owns jtc contiguous
//          cols (j = lane*jtc+k). First softmax shift-free; Z from scan.
//          Ph (f16 P) aliases Sc after a pre-read barrier.
// Phase 3: O = P V via mfma; wave w owns d-block w; B from vt global.
// ---------------------------------------------------------------------------
__global__ __launch_bounds__(256, 4) void k_attn(
    const f16* __restrict__ Qh, const f16* __restrict__ VT,
    f16* __restrict__ O, const float* __restrict__ gam, int maskflag)
{
    __shared__ float Sc[16][516];
    f16* Ph = (f16*)Sc;          // 16KB alias, safe after pre-read barrier

    int tid = threadIdx.x;
    int w = tid >> 6, lane = tid & 63;
    int ln = lane & 15, rg = lane >> 4;
    int tile = 31 - (blockIdx.x & 31);   // heavy-first within each bh
    int bh = blockIdx.x >> 5;
    int b = bh >> 3, h = bh & 7;
    int i0 = tile * 16;
    int jtc = (tile >> 2) + 1;          // valid j-tiles (64 cols each)
    int units = jtc * 4;                // 16-col units

    const f16* Qbase = Qh + ((size_t)b * Sl) * Dm + h * DKh;

    float gm = gam[h];
    float g = -((gm > 20.f) ? gm : log1pf(__expf(gm)));   // -softplus(gamma)

    // A-frags: Q rows i0..i0+15, reused across units
    f16x8 aq0 = *(const f16x8*)(Qbase + (size_t)(i0 + ln) * Dm + rg * 8);
    f16x8 aq1 = *(const f16x8*)(Qbase + (size_t)(i0 + ln) * Dm + 32 + rg * 8);

    // ---- Phase 1: scores, unit-parallel ---------------------------------
    for (int u = w; u < units; u += 4) {
        const f16* kb = Qbase + (size_t)(u * 16 + ln) * Dm + rg * 8;
        f16x8 b0 = *(const f16x8*)(kb);
        f16x8 b1 = *(const f16x8*)(kb + 32);
        f32x4 c = {};
        c = __builtin_amdgcn_mfma_f32_16x16x32_f16(aq0, b0, c, 0, 0, 0);
        c = __builtin_amdgcn_mfma_f32_16x16x32_f16(aq1, b1, c, 0, 0, 0);
#pragma unroll
        for (int r = 0; r < 4; ++r)
            Sc[rg * 4 + r][u * 16 + ln] = c[r];
    }
    __syncthreads();

    // ---- Phase 2a: pre-read this wave's 4 rows (before Ph overwrites Sc)
    int jbase = lane * jtc;
    float s4[4][8];
    if ((jtc & 3) == 0) {                      // 16B-aligned vector path
#pragma unroll
        for (int q = 0; q < 4; ++q) {
            int r = w * 4 + q;
            float4 t0 = *(float4*)&Sc[r][jbase];
            s4[q][0] = t0.x; s4[q][1] = t0.y; s4[q][2] = t0.z; s4[q][3] = t0.w;
            if (jtc == 8) {
                float4 t1 = *(float4*)&Sc[r][jbase + 4];
                s4[q][4] = t1.x; s4[q][5] = t1.y; s4[q][6] = t1.z; s4[q][7] = t1.w;
            }
        }
    } else {
#pragma unroll
        for (int q = 0; q < 4; ++q) {
            int r = w * 4 + q;
#pragma unroll
            for (int k = 0; k < 8; ++k)
                if (k < jtc) s4[q][k] = Sc[r][jbase + k];
        }
    }
    __syncthreads();   // all Sc reads done; Ph may now overwrite

    // ---- Phase 2b: softmax -> cumsum -> decay -> softmax ----------------
    for (int q = 0; q < 4; ++q) {
        int r = w * 4 + q;
        int i = i0 + r;
        int jmax = maskflag ? i : (i - 1);

        float sv[8], cs[8], pp[8];
        float run = 0.f;
#pragma unroll
        for (int k = 0; k < 8; ++k) if (k < jtc) {
            int j = jbase + k;
            float s = (j <= jmax) ? s4[q][k] * 0.125f : NEGV;
            sv[k] = s;
            float pe = __expf(s);      // exp(-1e32) = 0 for masked
            run += pe;
            cs[k] = run;               // per-lane inclusive sum
        }
        // inclusive scan across lanes (j-ordered); lane 63's value = Z
        float sl = run;
#pragma unroll
        for (int off = 1; off < 64; off <<= 1) {
            float nv = __shfl_up(sl, off);
            if (lane >= off) sl += nv;
        }
        float excl = sl - run;
        float Z = __shfl(sl, 63);
        float inv = 1.f / Z;

#pragma unroll
        for (int k = 0; k < 8; ++k) if (k < jtc) {
            int j = jbase + k;
            float rem = (Z - excl - cs[k]) * inv;     // disttot - distcum
            float pos = fabsf((float)(i - j));
            float dd = fmaxf(rem * pos, 0.f);         // fmax(NaN,0)=0 safe
            float te = __expf(sqrtf(dd) * g);
            te = fminf(fmaxf(te, 1e-5f), 1e5f);
            sv[k] = (j <= jmax) ? sv[k] * te : NEGV;
        }

        float m = NEGV;
#pragma unroll
        for (int k = 0; k < 8; ++k) if (k < jtc) m = fmaxf(m, sv[k]);
#pragma unroll
        for (int off = 32; off >= 1; off >>= 1) m = fmaxf(m, __shfl_xor(m, off));
        float Z2 = 0.f;
#pragma unroll
        for (int k = 0; k < 8; ++k) if (k < jtc) {
            pp[k] = __expf(sv[k] - m);
            Z2 += pp[k];
        }
#pragma unroll
        for (int off = 32; off >= 1; off >>= 1) Z2 += __shfl_xor(Z2, off);
        float inv2 = 1.f / Z2;

        int zp = (maskflag == 0) && (i == 0);
        // write P f16 into swizzled Ph (chunk cj, slot low3 ^= r&7)
        if (jtc == 8) {
            float a[8];
#pragma unroll
            for (int k = 0; k < 8; ++k) a[k] = zp ? 0.f : pp[k] * inv2;
            int slot = (lane & ~7) | ((lane & 7) ^ (r & 7));
            f16x8 o8 = { (f16)a[0], (f16)a[1], (f16)a[2], (f16)a[3],
                         (f16)a[4], (f16)a[5], (f16)a[6], (f16)a[7] };
            *(f16x8*)(Ph + r * 512 + slot * 8) = o8;
        } else {
#pragma unroll
            for (int k = 0; k < 8; ++k) if (k < jtc) {
                int j = jbase + k;
                int cj = j >> 3;
                int slot = (cj & ~7) | ((cj & 7) ^ (r & 7));
                float a = zp ? 0.f : pp[k] * inv2;
                Ph[r * 512 + slot * 8 + (j & 7)] = (f16)a;
            }
        }
    }
    __syncthreads();

    // ---- Phase 3: O = P @ V, wave w owns d-block nb=w -------------------
    f32x4 oa = {};
    for (int jt = 0; jt < jtc; ++jt) {
        int j0 = jt * 64;
#pragma unroll
        for (int ks = 0; ks < 2; ++ks) {
            int c = jt * 8 + ks * 4 + rg;
            int slot = (c & ~7) | ((c & 7) ^ (ln & 7));
            f16x8 ap = *(const f16x8*)(Ph + ln * 512 + slot * 8);
            const f16* vb_ = VT + ((size_t)bh * 64 + w * 16 + ln) * 512
                             + j0 + ks * 32 + rg * 8;
            f16x8 bv = *(const f16x8*)vb_;
            oa = __builtin_amdgcn_mfma_f32_16x16x32_f16(ap, bv, oa, 0, 0, 0);
        }
    }
    f16* ob = O + ((size_t)b * Sl + i0 + rg * 4) * Dm + h * DKh + w * 16 + ln;
#pragma unroll
    for (int r = 0; r < 4; ++r)
        ob[(size_t)r * Dm] = (f16)oa[r];
}

// ---------------------------------------------------------------------------
// Residual + LayerNorm: Out = LN(Xn + Rr)*g + b, dual f32+f16 output.
// ---------------------------------------------------------------------------
__global__ __launch_bounds__(256) void k_ln(
    const float* __restrict__ Xn, const float* __restrict__ Rr,
    const float* __restrict__ gw, const float* __restrict__ bw,
    float* __restrict__ Out, f16* __restrict__ Outh)
{
    int tid = threadIdx.x;
    int w = tid >> 6, lane = tid & 63;
    int row = blockIdx.x * 4 + w;
    const float* xr = Xn + (size_t)row * Dm;
    const float* rr = Rr + (size_t)row * Dm;
    float v[8], sum = 0.f;
#pragma unroll
    for (int r = 0; r < 8; ++r) {
        int c = lane + r * 64;
        v[r] = xr[c] + rr[c];
        sum += v[r];
    }
#pragma unroll
    for (int off = 32; off >= 1; off >>= 1) sum += __shfl_xor(sum, off);
    float mu = sum * (1.f / 512.f);
    float var = 0.f;
#pragma unroll
    for (int r = 0; r < 8; ++r) { float d = v[r] - mu; var += d * d; }
#pragma unroll
    for (int off = 32; off >= 1; off >>= 1) var += __shfl_xor(var, off);
    float rs = rsqrtf(var * (1.f / 512.f) + 1e-5f);
    float* orow = Out + (size_t)row * Dm;
    f16* ohrow = Outh + (size_t)row * Dm;
#pragma unroll
    for (int r = 0; r < 8; ++r) {
        int c = lane + r * 64;
        float val = (v[r] - mu) * rs * gw[c] + bw[c];
        orow[c] = val;
        ohrow[c] = (f16)val;
    }
}

// ---------------------------------------------------------------------------
extern "C" void kernel_launch(void* const* d_in, const int* in_sizes, int n_in,
                              void* d_out, int out_size, void* d_ws, size_t ws_size,
                              hipStream_t stream)
{
    const float* q_emb  = (const float*)d_in[0];
    const float* qa_emb = (const float*)d_in[1];
    const float* Wk  = (const float*)d_in[3];
    const float* bk  = (const float*)d_in[4];
    const float* Wv  = (const float*)d_in[5];
    const float* bv  = (const float*)d_in[6];
    const float* Wo  = (const float*)d_in[7];
    const float* bo  = (const float*)d_in[8];
    const float* gam = (const float*)d_in[9];
    const float* l1g = (const float*)d_in[10];
    const float* l1b = (const float*)d_in[11];
    const float* W1  = (const float*)d_in[12];
    const float* b1  = (const float*)d_in[13];
    const float* W2  = (const float*)d_in[14];
    const float* b2  = (const float*)d_in[15];
    const float* l2g = (const float*)d_in[16];
    const float* l2b = (const float*)d_in[17];
    float* outp = (float*)d_out;

    const size_t NE  = (size_t)MROWS * Dm;    // 4194304
    const size_t WDD = (size_t)Dm * Dm;
    const size_t WDF = (size_t)Dm * DFFn;

    float* xbuf = (float*)d_ws;               // NE f32
    float* ybuf = xbuf + NE;                  // NE f32
    float* t2   = ybuf + NE;                  // NE f32 (LN input temp)
    f16* xh  = (f16*)(t2 + NE);               // NE
    f16* yh  = xh + NE;                       // NE
    f16* R   = yh + NE;                       // 4*NE f16 region
    f16* qh  = R;                             // q(=k) heads f16
    f16* vt  = R + 2 * NE;                    // v transposed per head (fused)
    f16* t1h = R + 3 * NE;                    // attention output f16
    f16* fbh = R;                             // FFN hidden (aliases R, 4*NE)
    f16* wkh = R + 4 * NE;                    // weights f16
    f16* wvh = wkh + 6 * WDD;
    f16* woh = wvh + 6 * WDD;
    f16* w1h = woh + 6 * WDD;                 // slots 0,1,3,5
    f16* w2h = w1h + 4 * WDF;

    // ---- per-call weight convert+transpose (f32 [K,N] -> f16 [N,K]) ----
    k_wconv<<<dim3(Dm / 32, Dm / 32, 6), 256, 0, stream>>>(Wk, wkh, Dm, Dm, 0);
    k_wconv<<<dim3(Dm / 32, Dm / 32, 6), 256, 0, stream>>>(Wv, wvh, Dm, Dm, 0);
    k_wconv<<<dim3(Dm / 32, Dm / 32, 6), 256, 0, stream>>>(Wo, woh, Dm, Dm, 0);
    k_wconv<<<dim3(DFFn / 32, Dm / 32, 4), 256, 0, stream>>>(W1, w1h, Dm, DFFn, 1);
    k_wconv<<<dim3(Dm / 32, DFFn / 32, 4), 256, 0, stream>>>(W2, w2h, DFFn, Dm, 1);

    const int n = (int)NE;
    k_copy2<<<n / 256, 256, 0, stream>>>(q_emb,  xbuf, xh, n);
    k_copy2<<<n / 256, 256, 0, stream>>>(qa_emb, ybuf, yh, n);

    auto gemm16 = [&](const f16* A, const f16* Bt, const float* bias, f16* C,
                      int M, int N, int K) {
        k_gemm<0, 1, 0><<<dim3(N / 128, M / 128), 256, 0, stream>>>(A, Bt, bias, nullptr, C, M, N, K);
    };
    auto gemm32 = [&](const f16* A, const f16* Bt, const float* bias, float* C,
                      int M, int N, int K) {
        k_gemm<0, 0, 0><<<dim3(N / 128, M / 128), 256, 0, stream>>>(A, Bt, bias, C, nullptr, M, N, K);
    };
    auto gemmvt = [&](const f16* A, const f16* Bt, const float* bias, f16* C) {
        k_gemm<0, 1, 1><<<dim3(Dm / 128, MROWS / 128), 256, 0, stream>>>(A, Bt, bias, nullptr, C, MROWS, Dm, Dm);
    };

    // finalOut: if non-null, the LAST LayerNorm's f32 result goes there
    // (the f32 residual stream is dead afterwards; f16 mirror still written).
    auto layer = [&](int l, int maskflag, float* Xq, f16* Xqh, f16* Xvh,
                     bool apply_pos, float* finalOut) {
        gemm16(Xqh, wkh + (size_t)l * WDD, bk + l * Dm, qh, MROWS, Dm, Dm);
        gemmvt(Xvh, wvh + (size_t)l * WDD, bv + l * Dm, vt);
        k_attn<<<Bsz * Hn * 32, 256, 0, stream>>>(qh, vt, t1h, gam + l * Hn, maskflag);
        gemm32(t1h, woh + (size_t)l * WDD, bo + l * Dm, t2, MROWS, Dm, Dm);
        if (apply_pos) {
            k_ln<<<MROWS / 4, 256, 0, stream>>>(t2, Xq, l1g + l * Dm, l1b + l * Dm, Xq, Xqh);
            int sl = (l < 2) ? l : ((l + 1) >> 1);
            k_gemm<1, 1, 0><<<dim3(DFFn / 128, MROWS / 128), 256, 0, stream>>>(
                Xqh, w1h + (size_t)sl * WDF, b1 + l * DFFn, nullptr, fbh, MROWS, DFFn, Dm);
            k_gemm<0, 0, 0><<<dim3(Dm / 128, MROWS / 128), 256, 0, stream>>>(
                fbh, w2h + (size_t)sl * WDF, b2 + l * Dm, t2, nullptr, MROWS, Dm, DFFn);
            k_ln<<<MROWS / 4, 256, 0, stream>>>(t2, Xq, l2g + l * Dm, l2b + l * Dm,
                                                finalOut ? finalOut : Xq, Xqh);
        } else {
            k_ln<<<MROWS / 4, 256, 0, stream>>>(t2, Xq, l1g + l * Dm, l1b + l * Dm,
                                                finalOut ? finalOut : Xq, Xqh);
        }
    };

    const size_t NEo = NE;
    // blocks_1: self-attn on y, mask=1, FFN. Layer 1 is y's final write -> out+NE.
    layer(0, 1, ybuf, yh, yh, true, nullptr);
    layer(1, 1, ybuf, yh, yh, true, outp + NEo);
    // blocks_2: (mask=1, no FFN) then (mask=0, values=y, FFN), twice.
    // Layer 5 is x's final write -> out.
    layer(2, 1, xbuf, xh, xh, false, nullptr);
    layer(3, 0, xbuf, xh, yh, true, nullptr);
    layer(4, 1, xbuf, xh, xh, false, nullptr);
    layer(5, 0, xbuf, xh, yh, true, outp);
}

// Round 4
// 1330.006 us; speedup vs baseline: 1.0500x; 1.0418x over previous
//
#include <hip/hip_runtime.h>
#include <hip/hip_bf16.h>

// Problem constants (AKT core): B=16, S=512, D=512, H=8, DFF=2048, NB=2, L=6
#define Bsz  16
#define Sl   512
#define Dm   512
#define Hn   8
#define DKh  64
#define DFFn 2048
#define MROWS (Bsz * Sl)      // 8192
#define NEGV (-1e32f)

typedef _Float16 f16;
typedef f16 f16x8 __attribute__((ext_vector_type(8)));
typedef f16 f16x4 __attribute__((ext_vector_type(4)));
typedef float f32x4 __attribute__((ext_vector_type(4)));

// async global->LDS, 16B per lane: lds dst = wave-uniform base + lane*16
#define GLDS16(g, l) __builtin_amdgcn_global_load_lds( \
    (const __attribute__((address_space(1))) void*)(g), \
    (__attribute__((address_space(3))) void*)(l), 16, 0, 0)

// ---------------------------------------------------------------------------
// copies
// ---------------------------------------------------------------------------
__global__ void k_copy2(const float* __restrict__ in, float* __restrict__ out,
                        f16* __restrict__ outh, int n) {
    int i = blockIdx.x * 256 + threadIdx.x;
    if (i < n) { float v = in[i]; out[i] = v; outh[i] = (f16)v; }
}

// ---------------------------------------------------------------------------
// Weight convert+transpose: W[K,N] f32 -> Wt[N,K] f16 (per layer slice z).
// lmap=1 maps output slot z -> source layer {0,1,3,5}.
// ---------------------------------------------------------------------------
__global__ __launch_bounds__(256) void k_wconv(const float* __restrict__ src,
        f16* __restrict__ dst, int K, int N, int lmap)
{
    __shared__ float T[32][36];
    int z = blockIdx.z;
    int ls = lmap ? (z < 2 ? z : 2 * z - 1) : z;
    const float* S = src + (size_t)ls * K * N;
    f16* Dt = dst + (size_t)z * K * N;
    int n0 = blockIdx.x * 32, k0 = blockIdx.y * 32;
    int t = threadIdx.x;
    int r = t >> 3, c = (t & 7) * 4;
    float4 v = *(const float4*)(S + (size_t)(k0 + r) * N + n0 + c);
    T[r][c] = v.x; T[r][c + 1] = v.y; T[r][c + 2] = v.z; T[r][c + 3] = v.w;
    __syncthreads();
    int n = t >> 3, kq = (t & 7) * 4;
    f16x4 o = { (f16)T[kq][n], (f16)T[kq + 1][n], (f16)T[kq + 2][n], (f16)T[kq + 3][n] };
    *(f16x4*)(Dt + (size_t)(n0 + n) * K + k0 + kq) = o;
}

// ---------------------------------------------------------------------------
// MFMA f16 GEMM: C[M,N] = A[M,K] @ Bt[N,K]^T + bias[N]. A,Bt f16; bias f32.
// 128x128 tile, BK=32, 4 waves (2x2 of 64x64), 16x16x32 MFMA, 4x4 tiles/wave.
// 2-phase pipeline: LDS double-buffer, stage(t+1) issued BEFORE compute(t),
// single __syncthreads() (vmcnt drain) per K-step.
// VTOUT=1: write V-projection output directly in vt[bh][d][s] f16 layout.
// ---------------------------------------------------------------------------
template <int RELU, int OUT16, int VTOUT>
__global__ __launch_bounds__(256) void k_gemm(
    const f16* __restrict__ A, const f16* __restrict__ Bt,
    const float* __restrict__ bias, float* __restrict__ C, f16* __restrict__ Ch,
    int M, int N, int K)
{
    __shared__ f16 As[2 * 128 * 32];
    __shared__ f16 Bs[2 * 128 * 32];
    int tid = threadIdx.x;
    int w = tid >> 6, lane = tid & 63;
    int ln = lane & 15, rg = lane >> 4;
    int wr = w >> 1, wc = w & 1;
    int m0 = blockIdx.y * 128, n0 = blockIdx.x * 128;

    int s0 = tid, s1 = 256 + tid;
    int r0s = s0 >> 2, c0s = ((s0 & 3) ^ ((s0 >> 3) & 3));
    int r1s = s1 >> 2, c1s = ((s1 & 3) ^ ((s1 >> 3) & 3));

    const f16* a0 = A + (size_t)(m0 + r0s) * K + c0s * 8;
    const f16* a1 = A + (size_t)(m0 + r1s) * K + c1s * 8;
    const f16* b0 = Bt + (size_t)(n0 + r0s) * K + c0s * 8;
    const f16* b1 = Bt + (size_t)(n0 + r1s) * K + c1s * 8;

    int cc8 = (rg ^ ((ln >> 1) & 3)) * 8;

    f32x4 acc[4][4] = {};

    int nk = K >> 5;

    // prologue: stage K-step 0 into buffer 0
    {
        f16* lA = As + (size_t)(w * 64) * 8;
        f16* lB = Bs + (size_t)(w * 64) * 8;
        GLDS16(a0, lA);
        GLDS16(a1, lA + 2048);
        GLDS16(b0, lB);
        GLDS16(b1, lB + 2048);
    }
    __syncthreads();   // vmcnt(0) drain: buf0 ready

    int cur = 0;
    for (int t = 0; t < nk; ++t) {
        // issue next-tile loads FIRST (overlap with compute below)
        if (t + 1 < nk) {
            int kt = (t + 1) << 5;
            int nb = cur ^ 1;
            f16* lA = As + nb * 4096 + (size_t)(w * 64) * 8;
            f16* lB = Bs + nb * 4096 + (size_t)(w * 64) * 8;
            GLDS16(a0 + kt, lA);
            GLDS16(a1 + kt, lA + 2048);
            GLDS16(b0 + kt, lB);
            GLDS16(b1 + kt, lB + 2048);
        }

        const f16* Ab = As + cur * 4096;
        const f16* Bb = Bs + cur * 4096;
        f16x8 af[4], bf[4];
#pragma unroll
        for (int i = 0; i < 4; ++i) {
            int m = wr * 64 + i * 16 + ln;
            af[i] = *(const f16x8*)(Ab + m * 32 + cc8);
            int nn = wc * 64 + i * 16 + ln;
            bf[i] = *(const f16x8*)(Bb + nn * 32 + cc8);
        }
#pragma unroll
        for (int i = 0; i < 4; ++i)
#pragma unroll
            for (int j = 0; j < 4; ++j)
                acc[i][j] = __builtin_amdgcn_mfma_f32_16x16x32_f16(af[i], bf[j], acc[i][j], 0, 0, 0);

        __syncthreads();   // drains vmcnt(0): next buffer staged, reads done
        cur ^= 1;
    }

#pragma unroll
    for (int j = 0; j < 4; ++j) {
        int col = n0 + wc * 64 + j * 16 + ln;
        float bj = bias[col];
#pragma unroll
        for (int i = 0; i < 4; ++i) {
            int rb = m0 + wr * 64 + i * 16 + rg * 4;
            if (VTOUT) {
                // vt[((b*8+h)*64 + dk)*512 + s], s = 4 consecutive rows
                int bq = rb >> 9, s = rb & 511;
                int hh = col >> 6, dk = col & 63;
                f16x4 o;
#pragma unroll
                for (int r = 0; r < 4; ++r) o[r] = (f16)(acc[i][j][r] + bj);
                *(f16x4*)(Ch + (((size_t)(bq * 8 + hh) * 64 + dk) << 9) + s) = o;
            } else {
#pragma unroll
                for (int r = 0; r < 4; ++r) {
                    float v = acc[i][j][r] + bj;
                    if (RELU) v = fmaxf(v, 0.f);
                    if (OUT16) Ch[(size_t)(rb + r) * N + col] = (f16)v;
                    else       C [(size_t)(rb + r) * N + col] = v;
                }
            }
        }
    }
}

// ---------------------------------------------------------------------------
// AKT attention, MFMA. One block per (b, h, 16-row i-tile), 4 waves.
// XCD-chunked swizzle: lbid = (bid&7)*512 + bid>>3 -> each XCD owns 16
// complete bh-groups (2MB K+V working set, fits 4MB per-XCD L2). All 32
// tile-blocks of a bh-group share that XCD's L2 -> K/V re-reads become L2
// hits instead of HBM misses (was FETCH 61.5MB vs 16MB input).
// Heavy-first within each bh (tile = 31 - lbid&31) for LPT drain.
// Phase 1: S = Q K^T via mfma, 16-col unit granularity across waves.
//          C-frags -> LDS Sc f32, row stride 516 (2-way bank alias = free).
// Phase 2: jtc-scaled softmax/cumsum/decay/softmax; lane owns jtc contiguous
//          cols. First softmax shift-free; Z from scan. Ph aliases Sc.
// Phase 3: O = P V via mfma, V-frags PREFETCHED into regs: batch 1 (8 frags)
//          issued at kernel top (latency under phases 1-2), batch 2 after
//          the pre-phase-3 barrier (latency under batch-1 MFMAs).
// ---------------------------------------------------------------------------
__global__ __launch_bounds__(256, 4) void k_attn(
    const f16* __restrict__ Qh, const f16* __restrict__ VT,
    f16* __restrict__ O, const float* __restrict__ gam, int maskflag)
{
    __shared__ float Sc[16][516];
    f16* Ph = (f16*)Sc;          // 16KB alias, safe after pre-read barrier

    int tid = threadIdx.x;
    int w = tid >> 6, lane = tid & 63;
    int ln = lane & 15, rg = lane >> 4;

    // XCD-chunked bijective remap (4096 blocks, 8 XCDs, 512 each)
    int bid = blockIdx.x;
    int lbid = (bid & 7) * 512 + (bid >> 3);
    int tile = 31 - (lbid & 31);        // heavy-first within each bh
    int bh = lbid >> 5;
    int b = bh >> 3, h = bh & 7;
    int i0 = tile * 16;
    int jtc = (tile >> 2) + 1;          // valid j-tiles (64 cols each)
    int units = jtc * 4;                // 16-col units

    const f16* Qbase = Qh + ((size_t)b * Sl) * Dm + h * DKh;

    float gm = gam[h];
    float g = -((gm > 20.f) ? gm : log1pf(__expf(gm)));   // -softplus(gamma)

    // ---- V-frag prefetch, batch 1 (frags 0..7; all of phase 3 for jtc<=4).
    // Issued first: latency hides under phases 1-2. Static indices only.
    const f16* vbase = VT + ((size_t)bh * 64 + w * 16 + ln) * 512 + rg * 8;
    f16x8 vb0[8];
#pragma unroll
    for (int f = 0; f < 8; ++f)
        if (f < 2 * jtc)
            vb0[f] = *(const f16x8*)(vbase + (f >> 1) * 64 + (f & 1) * 32);

    // A-frags: Q rows i0..i0+15, reused across units
    f16x8 aq0 = *(const f16x8*)(Qbase + (size_t)(i0 + ln) * Dm + rg * 8);
    f16x8 aq1 = *(const f16x8*)(Qbase + (size_t)(i0 + ln) * Dm + 32 + rg * 8);

    // ---- Phase 1: scores, unit-parallel ---------------------------------
    for (int u = w; u < units; u += 4) {
        const f16* kb = Qbase + (size_t)(u * 16 + ln) * Dm + rg * 8;
        f16x8 b0 = *(const f16x8*)(kb);
        f16x8 b1 = *(const f16x8*)(kb + 32);
        f32x4 c = {};
        c = __builtin_amdgcn_mfma_f32_16x16x32_f16(aq0, b0, c, 0, 0, 0);
        c = __builtin_amdgcn_mfma_f32_16x16x32_f16(aq1, b1, c, 0, 0, 0);
#pragma unroll
        for (int r = 0; r < 4; ++r)
            Sc[rg * 4 + r][u * 16 + ln] = c[r];
    }
    __syncthreads();

    // ---- Phase 2a: pre-read this wave's 4 rows (before Ph overwrites Sc)
    int jbase = lane * jtc;
    float s4[4][8];
    if ((jtc & 3) == 0) {                      // 16B-aligned vector path
#pragma unroll
        for (int q = 0; q < 4; ++q) {
            int r = w * 4 + q;
            float4 t0 = *(float4*)&Sc[r][jbase];
            s4[q][0] = t0.x; s4[q][1] = t0.y; s4[q][2] = t0.z; s4[q][3] = t0.w;
            if (jtc == 8) {
                float4 t1 = *(float4*)&Sc[r][jbase + 4];
                s4[q][4] = t1.x; s4[q][5] = t1.y; s4[q][6] = t1.z; s4[q][7] = t1.w;
            }
        }
    } else {
#pragma unroll
        for (int q = 0; q < 4; ++q) {
            int r = w * 4 + q;
#pragma unroll
            for (int k = 0; k < 8; ++k)
                if (k < jtc) s4[q][k] = Sc[r][jbase + k];
        }
    }
    __syncthreads();   // all Sc reads done; Ph may now overwrite

    // ---- Phase 2b: softmax -> cumsum -> decay -> softmax ----------------
    for (int q = 0; q < 4; ++q) {
        int r = w * 4 + q;
        int i = i0 + r;
        int jmax = maskflag ? i : (i - 1);

        float sv[8], cs[8], pp[8];
        float run = 0.f;
#pragma unroll
        for (int k = 0; k < 8; ++k) if (k < jtc) {
            int j = jbase + k;
            float s = (j <= jmax) ? s4[q][k] * 0.125f : NEGV;
            sv[k] = s;
            float pe = __expf(s);      // exp(-1e32) = 0 for masked
            run += pe;
            cs[k] = run;               // per-lane inclusive sum
        }
        // inclusive scan across lanes (j-ordered); lane 63's value = Z
        float sl = run;
#pragma unroll
        for (int off = 1; off < 64; off <<= 1) {
            float nv = __shfl_up(sl, off);
            if (lane >= off) sl += nv;
        }
        float excl = sl - run;
        float Z = __shfl(sl, 63);
        float inv = 1.f / Z;

#pragma unroll
        for (int k = 0; k < 8; ++k) if (k < jtc) {
            int j = jbase + k;
            float rem = (Z - excl - cs[k]) * inv;     // disttot - distcum
            float pos = fabsf((float)(i - j));
            float dd = fmaxf(rem * pos, 0.f);         // fmax(NaN,0)=0 safe
            float te = __expf(sqrtf(dd) * g);
            te = fminf(fmaxf(te, 1e-5f), 1e5f);
            sv[k] = (j <= jmax) ? sv[k] * te : NEGV;
        }

        float m = NEGV;
#pragma unroll
        for (int k = 0; k < 8; ++k) if (k < jtc) m = fmaxf(m, sv[k]);
#pragma unroll
        for (int off = 32; off >= 1; off >>= 1) m = fmaxf(m, __shfl_xor(m, off));
        float Z2 = 0.f;
#pragma unroll
        for (int k = 0; k < 8; ++k) if (k < jtc) {
            pp[k] = __expf(sv[k] - m);
            Z2 += pp[k];
        }
#pragma unroll
        for (int off = 32; off >= 1; off >>= 1) Z2 += __shfl_xor(Z2, off);
        float inv2 = 1.f / Z2;

        int zp = (maskflag == 0) && (i == 0);
        // write P f16 into swizzled Ph (chunk cj, slot low3 ^= r&7)
        if (jtc == 8) {
            float a[8];
#pragma unroll
            for (int k = 0; k < 8; ++k) a[k] = zp ? 0.f : pp[k] * inv2;
            int slot = (lane & ~7) | ((lane & 7) ^ (r & 7));
            f16x8 o8 = { (f16)a[0], (f16)a[1], (f16)a[2], (f16)a[3],
                         (f16)a[4], (f16)a[5], (f16)a[6], (f16)a[7] };
            *(f16x8*)(Ph + r * 512 + slot * 8) = o8;
        } else {
#pragma unroll
            for (int k = 0; k < 8; ++k) if (k < jtc) {
                int j = jbase + k;
                int cj = j >> 3;
                int slot = (cj & ~7) | ((cj & 7) ^ (r & 7));
                float a = zp ? 0.f : pp[k] * inv2;
                Ph[r * 512 + slot * 8 + (j & 7)] = (f16)a;
            }
        }
    }
    __syncthreads();

    // ---- V-frag prefetch, batch 2 (frags 8..15, heavy tiles only):
    // issued before consuming batch 1 -> latency under 8 MFMAs + LDS reads.
    f16x8 vb1[8];
#pragma unroll
    for (int f = 8; f < 16; ++f)
        if (f < 2 * jtc)
            vb1[f - 8] = *(const f16x8*)(vbase + (f >> 1) * 64 + (f & 1) * 32);

    // ---- Phase 3: O = P @ V, wave w owns d-block nb=w -------------------
    f32x4 oa = {};
#pragma unroll
    for (int f = 0; f < 8; ++f) if (f < 2 * jtc) {
        int c = (f >> 1) * 8 + (f & 1) * 4 + rg;
        int slot = (c & ~7) | ((c & 7) ^ (ln & 7));
        f16x8 ap = *(const f16x8*)(Ph + ln * 512 + slot * 8);
        oa = __builtin_amdgcn_mfma_f32_16x16x32_f16(ap, vb0[f], oa, 0, 0, 0);
    }
#pragma unroll
    for (int f = 8; f < 16; ++f) if (f < 2 * jtc) {
        int c = (f >> 1) * 8 + (f & 1) * 4 + rg;
        int slot = (c & ~7) | ((c & 7) ^ (ln & 7));
        f16x8 ap = *(const f16x8*)(Ph + ln * 512 + slot * 8);
        oa = __builtin_amdgcn_mfma_f32_16x16x32_f16(ap, vb1[f - 8], oa, 0, 0, 0);
    }

    f16* ob = O + ((size_t)b * Sl + i0 + rg * 4) * Dm + h * DKh + w * 16 + ln;
#pragma unroll
    for (int r = 0; r < 4; ++r)
        ob[(size_t)r * Dm] = (f16)oa[r];
}

// ---------------------------------------------------------------------------
// Residual + LayerNorm: Out = LN(Xn + Rr)*g + b, dual f32+f16 output.
// ---------------------------------------------------------------------------
__global__ __launch_bounds__(256) void k_ln(
    const float* __restrict__ Xn, const float* __restrict__ Rr,
    const float* __restrict__ gw, const float* __restrict__ bw,
    float* __restrict__ Out, f16* __restrict__ Outh)
{
    int tid = threadIdx.x;
    int w = tid >> 6, lane = tid & 63;
    int row = blockIdx.x * 4 + w;
    const float* xr = Xn + (size_t)row * Dm;
    const float* rr = Rr + (size_t)row * Dm;
    float v[8], sum = 0.f;
#pragma unroll
    for (int r = 0; r < 8; ++r) {
        int c = lane + r * 64;
        v[r] = xr[c] + rr[c];
        sum += v[r];
    }
#pragma unroll
    for (int off = 32; off >= 1; off >>= 1) sum += __shfl_xor(sum, off);
    float mu = sum * (1.f / 512.f);
    float var = 0.f;
#pragma unroll
    for (int r = 0; r < 8; ++r) { float d = v[r] - mu; var += d * d; }
#pragma unroll
    for (int off = 32; off >= 1; off >>= 1) var += __shfl_xor(var, off);
    float rs = rsqrtf(var * (1.f / 512.f) + 1e-5f);
    float* orow = Out + (size_t)row * Dm;
    f16* ohrow = Outh + (size_t)row * Dm;
#pragma unroll
    for (int r = 0; r < 8; ++r) {
        int c = lane + r * 64;
        float val = (v[r] - mu) * rs * gw[c] + bw[c];
        orow[c] = val;
        ohrow[c] = (f16)val;
    }
}

// ---------------------------------------------------------------------------
extern "C" void kernel_launch(void* const* d_in, const int* in_sizes, int n_in,
                              void* d_out, int out_size, void* d_ws, size_t ws_size,
                              hipStream_t stream)
{
    const float* q_emb  = (const float*)d_in[0];
    const float* qa_emb = (const float*)d_in[1];
    const float* Wk  = (const float*)d_in[3];
    const float* bk  = (const float*)d_in[4];
    const float* Wv  = (const float*)d_in[5];
    const float* bv  = (const float*)d_in[6];
    const float* Wo  = (const float*)d_in[7];
    const float* bo  = (const float*)d_in[8];
    const float* gam = (const float*)d_in[9];
    const float* l1g = (const float*)d_in[10];
    const float* l1b = (const float*)d_in[11];
    const float* W1  = (const float*)d_in[12];
    const float* b1  = (const float*)d_in[13];
    const float* W2  = (const float*)d_in[14];
    const float* b2  = (const float*)d_in[15];
    const float* l2g = (const float*)d_in[16];
    const float* l2b = (const float*)d_in[17];
    float* outp = (float*)d_out;

    const size_t NE  = (size_t)MROWS * Dm;    // 4194304
    const size_t WDD = (size_t)Dm * Dm;
    const size_t WDF = (size_t)Dm * DFFn;

    float* xbuf = (float*)d_ws;               // NE f32
    float* ybuf = xbuf + NE;                  // NE f32
    float* t2   = ybuf + NE;                  // NE f32 (LN input temp)
    f16* xh  = (f16*)(t2 + NE);               // NE
    f16* yh  = xh + NE;                       // NE
    f16* R   = yh + NE;                       // 4*NE f16 region
    f16* qh  = R;                             // q(=k) heads f16
    f16* vt  = R + 2 * NE;                    // v transposed per head (fused)
    f16* t1h = R + 3 * NE;                    // attention output f16
    f16* fbh = R;                             // FFN hidden (aliases R, 4*NE)
    f16* wkh = R + 4 * NE;                    // weights f16
    f16* wvh = wkh + 6 * WDD;
    f16* woh = wvh + 6 * WDD;
    f16* w1h = woh + 6 * WDD;                 // slots 0,1,3,5
    f16* w2h = w1h + 4 * WDF;

    // ---- per-call weight convert+transpose (f32 [K,N] -> f16 [N,K]) ----
    k_wconv<<<dim3(Dm / 32, Dm / 32, 6), 256, 0, stream>>>(Wk, wkh, Dm, Dm, 0);
    k_wconv<<<dim3(Dm / 32, Dm / 32, 6), 256, 0, stream>>>(Wv, wvh, Dm, Dm, 0);
    k_wconv<<<dim3(Dm / 32, Dm / 32, 6), 256, 0, stream>>>(Wo, woh, Dm, Dm, 0);
    k_wconv<<<dim3(DFFn / 32, Dm / 32, 4), 256, 0, stream>>>(W1, w1h, Dm, DFFn, 1);
    k_wconv<<<dim3(Dm / 32, DFFn / 32, 4), 256, 0, stream>>>(W2, w2h, DFFn, Dm, 1);

    const int n = (int)NE;
    k_copy2<<<n / 256, 256, 0, stream>>>(q_emb,  xbuf, xh, n);
    k_copy2<<<n / 256, 256, 0, stream>>>(qa_emb, ybuf, yh, n);

    auto gemm16 = [&](const f16* A, const f16* Bt, const float* bias, f16* C,
                      int M, int N, int K) {
        k_gemm<0, 1, 0><<<dim3(N / 128, M / 128), 256, 0, stream>>>(A, Bt, bias, nullptr, C, M, N, K);
    };
    auto gemm32 = [&](const f16* A, const f16* Bt, const float* bias, float* C,
                      int M, int N, int K) {
        k_gemm<0, 0, 0><<<dim3(N / 128, M / 128), 256, 0, stream>>>(A, Bt, bias, C, nullptr, M, N, K);
    };
    auto gemmvt = [&](const f16* A, const f16* Bt, const float* bias, f16* C) {
        k_gemm<0, 1, 1><<<dim3(Dm / 128, MROWS / 128), 256, 0, stream>>>(A, Bt, bias, nullptr, C, MROWS, Dm, Dm);
    };

    // finalOut: if non-null, the LAST LayerNorm's f32 result goes there
    // (the f32 residual stream is dead afterwards; f16 mirror still written).
    auto layer = [&](int l, int maskflag, float* Xq, f16* Xqh, f16* Xvh,
                     bool apply_pos, float* finalOut) {
        gemm16(Xqh, wkh + (size_t)l * WDD, bk + l * Dm, qh, MROWS, Dm, Dm);
        gemmvt(Xvh, wvh + (size_t)l * WDD, bv + l * Dm, vt);
        k_attn<<<Bsz * Hn * 32, 256, 0, stream>>>(qh, vt, t1h, gam + l * Hn, maskflag);
        gemm32(t1h, woh + (size_t)l * WDD, bo + l * Dm, t2, MROWS, Dm, Dm);
        if (apply_pos) {
            k_ln<<<MROWS / 4, 256, 0, stream>>>(t2, Xq, l1g + l * Dm, l1b + l * Dm, Xq, Xqh);
            int sl = (l < 2) ? l : ((l + 1) >> 1);
            k_gemm<1, 1, 0><<<dim3(DFFn / 128, MROWS / 128), 256, 0, stream>>>(
                Xqh, w1h + (size_t)sl * WDF, b1 + l * DFFn, nullptr, fbh, MROWS, DFFn, Dm);
            k_gemm<0, 0, 0><<<dim3(Dm / 128, MROWS / 128), 256, 0, stream>>>(
                fbh, w2h + (size_t)sl * WDF, b2 + l * Dm, t2, nullptr, MROWS, Dm, DFFn);
            k_ln<<<MROWS / 4, 256, 0, stream>>>(t2, Xq, l2g + l * Dm, l2b + l * Dm,
                                                finalOut ? finalOut : Xq, Xqh);
        } else {
            k_ln<<<MROWS / 4, 256, 0, stream>>>(t2, Xq, l1g + l * Dm, l1b + l * Dm,
                                                finalOut ? finalOut : Xq, Xqh);
        }
    };

    const size_t NEo = NE;
    // blocks_1: self-attn on y, mask=1, FFN. Layer 1 is y's final write -> out+NE.
    layer(0, 1, ybuf, yh, yh, true, nullptr);
    layer(1, 1, ybuf, yh, yh, true, outp + NEo);
    // blocks_2: (mask=1, no FFN) then (mask=0, values=y, FFN), twice.
    // Layer 5 is x's final write -> out.
    layer(2, 1, xbuf, xh, xh, false, nullptr);
    layer(3, 0, xbuf, xh, yh, true, nullptr);
    layer(4, 1, xbuf, xh, xh, false, nullptr);
    layer(5, 0, xbuf, xh, yh, true, outp);
}

// Round 5
// 1185.937 us; speedup vs baseline: 1.1775x; 1.1215x over previous
//
#include <hip/hip_runtime.h>
#include <hip/hip_bf16.h>

// Problem constants (AKT core): B=16, S=512, D=512, H=8, DFF=2048, NB=2, L=6
#define Bsz  16
#define Sl   512
#define Dm   512
#define Hn   8
#define DKh  64
#define DFFn 2048
#define MROWS (Bsz * Sl)      // 8192
#define NEGV (-1e32f)

typedef _Float16 f16;
typedef f16 f16x8 __attribute__((ext_vector_type(8)));
typedef f16 f16x4 __attribute__((ext_vector_type(4)));
typedef float f32x4 __attribute__((ext_vector_type(4)));

// async global->LDS, 16B per lane: lds dst = wave-uniform base + lane*16
#define GLDS16(g, l) __builtin_amdgcn_global_load_lds( \
    (const __attribute__((address_space(1))) void*)(g), \
    (__attribute__((address_space(3))) void*)(l), 16, 0, 0)

// ---------------------------------------------------------------------------
// copies
// ---------------------------------------------------------------------------
__global__ void k_copy2(const float* __restrict__ in, float* __restrict__ out,
                        f16* __restrict__ outh, int n) {
    int i = blockIdx.x * 256 + threadIdx.x;
    if (i < n) { float v = in[i]; out[i] = v; outh[i] = (f16)v; }
}

// ---------------------------------------------------------------------------
// Weight convert+transpose: W[K,N] f32 -> Wt[N,K] f16 (per layer slice z).
// lmap=1 maps output slot z -> source layer {0,1,3,5}.
// ---------------------------------------------------------------------------
__global__ __launch_bounds__(256) void k_wconv(const float* __restrict__ src,
        f16* __restrict__ dst, int K, int N, int lmap)
{
    __shared__ float T[32][36];
    int z = blockIdx.z;
    int ls = lmap ? (z < 2 ? z : 2 * z - 1) : z;
    const float* S = src + (size_t)ls * K * N;
    f16* Dt = dst + (size_t)z * K * N;
    int n0 = blockIdx.x * 32, k0 = blockIdx.y * 32;
    int t = threadIdx.x;
    int r = t >> 3, c = (t & 7) * 4;
    float4 v = *(const float4*)(S + (size_t)(k0 + r) * N + n0 + c);
    T[r][c] = v.x; T[r][c + 1] = v.y; T[r][c + 2] = v.z; T[r][c + 3] = v.w;
    __syncthreads();
    int n = t >> 3, kq = (t & 7) * 4;
    f16x4 o = { (f16)T[kq][n], (f16)T[kq + 1][n], (f16)T[kq + 2][n], (f16)T[kq + 3][n] };
    *(f16x4*)(Dt + (size_t)(n0 + n) * K + k0 + kq) = o;
}

// ---------------------------------------------------------------------------
// MFMA f16 GEMM: C[M,N] = A[M,K] @ Bt[N,K]^T + bias[N]. A,Bt f16; bias f32.
// 128x128 tile, 4 waves (2x2 of 64x64), 16x16x32 MFMA, 4x4 tiles/wave.
// BK64=1: K-step 64 (two 32-wide halves, same per-half layout/swizzle) —
//   halves barrier count, doubles compute per vmcnt drain. LDS 64KB; used
//   only for grids <= 256 blocks (1 block/CU -> no occupancy cost).
// 2-phase pipeline: stage(t+1) issued BEFORE compute(t), one barrier/step.
// VTOUT=1: write V-projection output directly in vt[bh][d][s] f16 layout.
// ---------------------------------------------------------------------------
template <int RELU, int OUT16, int VTOUT, int BK64>
__global__ __launch_bounds__(256) void k_gemm(
    const f16* __restrict__ A, const f16* __restrict__ Bt,
    const float* __restrict__ bias, float* __restrict__ C, f16* __restrict__ Ch,
    int M, int N, int K)
{
    constexpr int HL = BK64 ? 2 : 1;        // 32-wide halves per K-step
    constexpr int BUF = HL * 4096;          // f16 per buffer per matrix
    __shared__ f16 As[2 * BUF];
    __shared__ f16 Bs[2 * BUF];
    int tid = threadIdx.x;
    int w = tid >> 6, lane = tid & 63;
    int ln = lane & 15, rg = lane >> 4;
    int wr = w >> 1, wc = w & 1;
    int m0 = blockIdx.y * 128, n0 = blockIdx.x * 128;

    int s0 = tid, s1 = 256 + tid;
    int r0s = s0 >> 2, c0s = ((s0 & 3) ^ ((s0 >> 3) & 3));
    int r1s = s1 >> 2, c1s = ((s1 & 3) ^ ((s1 >> 3) & 3));

    const f16* a0 = A + (size_t)(m0 + r0s) * K + c0s * 8;
    const f16* a1 = A + (size_t)(m0 + r1s) * K + c1s * 8;
    const f16* b0 = Bt + (size_t)(n0 + r0s) * K + c0s * 8;
    const f16* b1 = Bt + (size_t)(n0 + r1s) * K + c1s * 8;

    int cc8 = (rg ^ ((ln >> 1) & 3)) * 8;

    f32x4 acc[4][4] = {};

    int nk = K >> (BK64 ? 6 : 5);

    auto STAGE = [&](int nb, int kt) {
        f16* lA = As + nb * BUF + w * 512;
        f16* lB = Bs + nb * BUF + w * 512;
        GLDS16(a0 + kt, lA);
        GLDS16(a1 + kt, lA + 2048);
        GLDS16(b0 + kt, lB);
        GLDS16(b1 + kt, lB + 2048);
        if (BK64) {
            GLDS16(a0 + kt + 32, lA + 4096);
            GLDS16(a1 + kt + 32, lA + 4096 + 2048);
            GLDS16(b0 + kt + 32, lB + 4096);
            GLDS16(b1 + kt + 32, lB + 4096 + 2048);
        }
    };

    STAGE(0, 0);
    __syncthreads();   // vmcnt(0) drain: buf0 ready

    int cur = 0;
    for (int t = 0; t < nk; ++t) {
        if (t + 1 < nk) STAGE(cur ^ 1, (t + 1) << (BK64 ? 6 : 5));

#pragma unroll
        for (int hh = 0; hh < HL; ++hh) {
            const f16* Ab = As + cur * BUF + hh * 4096;
            const f16* Bb = Bs + cur * BUF + hh * 4096;
            f16x8 af[4], bf[4];
#pragma unroll
            for (int i = 0; i < 4; ++i) {
                int m = wr * 64 + i * 16 + ln;
                af[i] = *(const f16x8*)(Ab + m * 32 + cc8);
                int nn = wc * 64 + i * 16 + ln;
                bf[i] = *(const f16x8*)(Bb + nn * 32 + cc8);
            }
#pragma unroll
            for (int i = 0; i < 4; ++i)
#pragma unroll
                for (int j = 0; j < 4; ++j)
                    acc[i][j] = __builtin_amdgcn_mfma_f32_16x16x32_f16(af[i], bf[j], acc[i][j], 0, 0, 0);
        }

        __syncthreads();   // drains vmcnt(0): next buffer staged, reads done
        cur ^= 1;
    }

#pragma unroll
    for (int j = 0; j < 4; ++j) {
        int col = n0 + wc * 64 + j * 16 + ln;
        float bj = bias[col];
#pragma unroll
        for (int i = 0; i < 4; ++i) {
            int rb = m0 + wr * 64 + i * 16 + rg * 4;
            if (VTOUT) {
                // vt[((b*8+h)*64 + dk)*512 + s], s = 4 consecutive rows
                int bq = rb >> 9, s = rb & 511;
                int hh = col >> 6, dk = col & 63;
                f16x4 o;
#pragma unroll
                for (int r = 0; r < 4; ++r) o[r] = (f16)(acc[i][j][r] + bj);
                *(f16x4*)(Ch + (((size_t)(bq * 8 + hh) * 64 + dk) << 9) + s) = o;
            } else {
#pragma unroll
                for (int r = 0; r < 4; ++r) {
                    float v = acc[i][j][r] + bj;
                    if (RELU) v = fmaxf(v, 0.f);
                    if (OUT16) Ch[(size_t)(rb + r) * N + col] = (f16)v;
                    else       C [(size_t)(rb + r) * N + col] = v;
                }
            }
        }
    }
}

// ---------------------------------------------------------------------------
// AKT attention, MFMA. One block per (b, h, 16-row i-tile), 4 waves.
// XCD-chunked swizzle (proven: FETCH 61.5->14.4MB): lbid=(bid&7)*512+bid>>3.
// Heavy-first within each bh (tile = 31 - lbid&31) for LPT drain.
// Phase 1: S = Q K^T via mfma, 16-col unit granularity across waves.
//          C-frags -> LDS Sc f32, row stride 516 (2-way bank alias = free).
// Phase 2: INTERLEAVED 4-row softmax/cumsum/decay/softmax: the 4 rows owned
//          by a wave are processed as unrolled arrays so their serial
//          shuffle chains (scan 6 + sum 6 dependent ds_bpermutes) overlap.
//          Both softmaxes shift-free (|s|, |s*te| are O(6): exp f32-safe;
//          ratios shift-invariant). Ph aliases Sc after pre-read barrier.
// Phase 3: O = P V via mfma, inline V loads (L2-resident after swizzle),
//          DUAL accumulators to break the 16-deep serial mfma chain.
// ---------------------------------------------------------------------------
__global__ __launch_bounds__(256, 4) void k_attn(
    const f16* __restrict__ Qh, const f16* __restrict__ VT,
    f16* __restrict__ O, const float* __restrict__ gam, int maskflag)
{
    __shared__ float Sc[16][516];
    f16* Ph = (f16*)Sc;          // 16KB alias, safe after pre-read barrier

    int tid = threadIdx.x;
    int w = tid >> 6, lane = tid & 63;
    int ln = lane & 15, rg = lane >> 4;

    // XCD-chunked bijective remap (4096 blocks, 8 XCDs, 512 each)
    int bid = blockIdx.x;
    int lbid = (bid & 7) * 512 + (bid >> 3);
    int tile = 31 - (lbid & 31);        // heavy-first within each bh
    int bh = lbid >> 5;
    int b = bh >> 3, h = bh & 7;
    int i0 = tile * 16;
    int jtc = (tile >> 2) + 1;          // valid j-tiles (64 cols each)
    int units = jtc * 4;                // 16-col units

    const f16* Qbase = Qh + ((size_t)b * Sl) * Dm + h * DKh;

    float gm = gam[h];
    float g = -((gm > 20.f) ? gm : log1pf(__expf(gm)));   // -softplus(gamma)

    // A-frags: Q rows i0..i0+15, reused across units
    f16x8 aq0 = *(const f16x8*)(Qbase + (size_t)(i0 + ln) * Dm + rg * 8);
    f16x8 aq1 = *(const f16x8*)(Qbase + (size_t)(i0 + ln) * Dm + 32 + rg * 8);

    // ---- Phase 1: scores, unit-parallel ---------------------------------
    for (int u = w; u < units; u += 4) {
        const f16* kb = Qbase + (size_t)(u * 16 + ln) * Dm + rg * 8;
        f16x8 b0 = *(const f16x8*)(kb);
        f16x8 b1 = *(const f16x8*)(kb + 32);
        f32x4 c = {};
        c = __builtin_amdgcn_mfma_f32_16x16x32_f16(aq0, b0, c, 0, 0, 0);
        c = __builtin_amdgcn_mfma_f32_16x16x32_f16(aq1, b1, c, 0, 0, 0);
#pragma unroll
        for (int r = 0; r < 4; ++r)
            Sc[rg * 4 + r][u * 16 + ln] = c[r];
    }
    __syncthreads();

    // ---- Phase 2a: pre-read this wave's 4 rows (before Ph overwrites Sc)
    int jbase = lane * jtc;
    float st[4][8];
    if ((jtc & 3) == 0) {                      // 16B-aligned vector path
#pragma unroll
        for (int q = 0; q < 4; ++q) {
            int r = w * 4 + q;
            float4 t0 = *(float4*)&Sc[r][jbase];
            st[q][0] = t0.x; st[q][1] = t0.y; st[q][2] = t0.z; st[q][3] = t0.w;
            if (jtc == 8) {
                float4 t1 = *(float4*)&Sc[r][jbase + 4];
                st[q][4] = t1.x; st[q][5] = t1.y; st[q][6] = t1.z; st[q][7] = t1.w;
            }
        }
    } else {
#pragma unroll
        for (int q = 0; q < 4; ++q) {
            int r = w * 4 + q;
#pragma unroll
            for (int k = 0; k < 8; ++k)
                if (k < jtc) st[q][k] = Sc[r][jbase + k];
        }
    }
    __syncthreads();   // all Sc reads done; Ph may now overwrite

    // ---- Phase 2b: interleaved 4-row softmax -> cumsum -> decay -> softmax
    int im = i0 + w * 4;
    float cs[4][8], run[4], sl[4];
#pragma unroll
    for (int q = 0; q < 4; ++q) {
        int jmax = maskflag ? (im + q) : (im + q - 1);
        run[q] = 0.f;
#pragma unroll
        for (int k = 0; k < 8; ++k) if (k < jtc) {
            int j = jbase + k;
            float s = (j <= jmax) ? st[q][k] * 0.125f : NEGV;
            st[q][k] = s;
            run[q] += __expf(s);       // exp(-1e32) = 0 for masked
            cs[q][k] = run[q];
        }
        sl[q] = run[q];
    }
    // 4 interleaved inclusive scans (latency of dependent shuffles overlaps)
#pragma unroll
    for (int off = 1; off < 64; off <<= 1) {
        float n0 = __shfl_up(sl[0], off);
        float n1 = __shfl_up(sl[1], off);
        float n2 = __shfl_up(sl[2], off);
        float n3 = __shfl_up(sl[3], off);
        if (lane >= off) { sl[0] += n0; sl[1] += n1; sl[2] += n2; sl[3] += n3; }
    }
    float Z2[4];
#pragma unroll
    for (int q = 0; q < 4; ++q) {
        float excl = sl[q] - run[q];
        float Z = __shfl(sl[q], 63);
        float inv = 1.f / Z;
        int i = im + q;
        int jmax = maskflag ? i : (i - 1);
        float z2 = 0.f;
#pragma unroll
        for (int k = 0; k < 8; ++k) if (k < jtc) {
            int j = jbase + k;
            float rem = (Z - excl - cs[q][k]) * inv;  // disttot - distcum
            float pos = fabsf((float)(i - j));
            float dd = fmaxf(rem * pos, 0.f);         // fmax(NaN,0)=0 safe
            float te = __expf(sqrtf(dd) * g);
            te = fminf(fmaxf(te, 1e-5f), 1e5f);
            float sc = (j <= jmax) ? st[q][k] * te : NEGV;
            float pe = __expf(sc);                    // shift-free, |sc| small
            st[q][k] = pe;
            z2 += pe;
        }
        Z2[q] = z2;
    }
    // 4 interleaved sum reductions
#pragma unroll
    for (int off = 32; off >= 1; off >>= 1) {
        Z2[0] += __shfl_xor(Z2[0], off);
        Z2[1] += __shfl_xor(Z2[1], off);
        Z2[2] += __shfl_xor(Z2[2], off);
        Z2[3] += __shfl_xor(Z2[3], off);
    }
#pragma unroll
    for (int q = 0; q < 4; ++q) {
        int r = w * 4 + q;
        int i = im + q;
        float inv2 = 1.f / Z2[q];
        int zp = (maskflag == 0) && (i == 0);
        // write P f16 into swizzled Ph (chunk cj, slot low3 ^= r&7)
        if (jtc == 8) {
            int slot = (lane & ~7) | ((lane & 7) ^ (r & 7));
            f16x8 o8;
#pragma unroll
            for (int k = 0; k < 8; ++k)
                o8[k] = (f16)(zp ? 0.f : st[q][k] * inv2);
            *(f16x8*)(Ph + r * 512 + slot * 8) = o8;
        } else {
#pragma unroll
            for (int k = 0; k < 8; ++k) if (k < jtc) {
                int j = jbase + k;
                int cj = j >> 3;
                int slot = (cj & ~7) | ((cj & 7) ^ (r & 7));
                float a = zp ? 0.f : st[q][k] * inv2;
                Ph[r * 512 + slot * 8 + (j & 7)] = (f16)a;
            }
        }
    }
    __syncthreads();

    // ---- Phase 3: O = P @ V, wave w owns d-block nb=w; dual accumulator --
    const f16* vbase = VT + ((size_t)bh * 64 + w * 16 + ln) * 512 + rg * 8;
    f32x4 oa0 = {}, oa1 = {};
#pragma unroll
    for (int f = 0; f < 16; ++f) if (f < 2 * jtc) {
        f16x8 bv = *(const f16x8*)(vbase + (f >> 1) * 64 + (f & 1) * 32);
        int c = (f >> 1) * 8 + (f & 1) * 4 + rg;
        int slot = (c & ~7) | ((c & 7) ^ (ln & 7));
        f16x8 ap = *(const f16x8*)(Ph + ln * 512 + slot * 8);
        if (f & 1) oa1 = __builtin_amdgcn_mfma_f32_16x16x32_f16(ap, bv, oa1, 0, 0, 0);
        else       oa0 = __builtin_amdgcn_mfma_f32_16x16x32_f16(ap, bv, oa0, 0, 0, 0);
    }
    f32x4 oa = oa0 + oa1;

    f16* ob = O + ((size_t)b * Sl + i0 + rg * 4) * Dm + h * DKh + w * 16 + ln;
#pragma unroll
    for (int r = 0; r < 4; ++r)
        ob[(size_t)r * Dm] = (f16)oa[r];
}

// ---------------------------------------------------------------------------
// Residual + LayerNorm: Out = LN(Xn + Rr)*g + b, dual f32+f16 output.
// Vectorized: float4 loads/stores (16B/lane), f16x4 half-store.
// ---------------------------------------------------------------------------
__global__ __launch_bounds__(256) void k_ln(
    const float* __restrict__ Xn, const float* __restrict__ Rr,
    const float* __restrict__ gw, const float* __restrict__ bw,
    float* __restrict__ Out, f16* __restrict__ Outh)
{
    int tid = threadIdx.x;
    int w = tid >> 6, lane = tid & 63;
    int row = blockIdx.x * 4 + w;
    const float* xr = Xn + (size_t)row * Dm;
    const float* rr = Rr + (size_t)row * Dm;
    int c0 = lane * 4, c1 = 256 + lane * 4;
    float4 va = *(const float4*)(xr + c0);
    float4 vb = *(const float4*)(xr + c1);
    float4 ra = *(const float4*)(rr + c0);
    float4 rb = *(const float4*)(rr + c1);
    va.x += ra.x; va.y += ra.y; va.z += ra.z; va.w += ra.w;
    vb.x += rb.x; vb.y += rb.y; vb.z += rb.z; vb.w += rb.w;
    float sum = va.x + va.y + va.z + va.w + vb.x + vb.y + vb.z + vb.w;
#pragma unroll
    for (int off = 32; off >= 1; off >>= 1) sum += __shfl_xor(sum, off);
    float mu = sum * (1.f / 512.f);
    float var = 0.f;
    {
        float d;
        d = va.x - mu; var += d * d;  d = va.y - mu; var += d * d;
        d = va.z - mu; var += d * d;  d = va.w - mu; var += d * d;
        d = vb.x - mu; var += d * d;  d = vb.y - mu; var += d * d;
        d = vb.z - mu; var += d * d;  d = vb.w - mu; var += d * d;
    }
#pragma unroll
    for (int off = 32; off >= 1; off >>= 1) var += __shfl_xor(var, off);
    float rs = rsqrtf(var * (1.f / 512.f) + 1e-5f);
    float4 ga = *(const float4*)(gw + c0);
    float4 gb = *(const float4*)(gw + c1);
    float4 ba = *(const float4*)(bw + c0);
    float4 bb = *(const float4*)(bw + c1);
    float4 oa, ob;
    oa.x = (va.x - mu) * rs * ga.x + ba.x;  oa.y = (va.y - mu) * rs * ga.y + ba.y;
    oa.z = (va.z - mu) * rs * ga.z + ba.z;  oa.w = (va.w - mu) * rs * ga.w + ba.w;
    ob.x = (vb.x - mu) * rs * gb.x + bb.x;  ob.y = (vb.y - mu) * rs * gb.y + bb.y;
    ob.z = (vb.z - mu) * rs * gb.z + bb.z;  ob.w = (vb.w - mu) * rs * gb.w + bb.w;
    float* orow = Out + (size_t)row * Dm;
    f16* ohrow = Outh + (size_t)row * Dm;
    *(float4*)(orow + c0) = oa;
    *(float4*)(orow + c1) = ob;
    f16x4 ha = { (f16)oa.x, (f16)oa.y, (f16)oa.z, (f16)oa.w };
    f16x4 hb = { (f16)ob.x, (f16)ob.y, (f16)ob.z, (f16)ob.w };
    *(f16x4*)(ohrow + c0) = ha;
    *(f16x4*)(ohrow + c1) = hb;
}

// ---------------------------------------------------------------------------
extern "C" void kernel_launch(void* const* d_in, const int* in_sizes, int n_in,
                              void* d_out, int out_size, void* d_ws, size_t ws_size,
                              hipStream_t stream)
{
    const float* q_emb  = (const float*)d_in[0];
    const float* qa_emb = (const float*)d_in[1];
    const float* Wk  = (const float*)d_in[3];
    const float* bk  = (const float*)d_in[4];
    const float* Wv  = (const float*)d_in[5];
    const float* bv  = (const float*)d_in[6];
    const float* Wo  = (const float*)d_in[7];
    const float* bo  = (const float*)d_in[8];
    const float* gam = (const float*)d_in[9];
    const float* l1g = (const float*)d_in[10];
    const float* l1b = (const float*)d_in[11];
    const float* W1  = (const float*)d_in[12];
    const float* b1  = (const float*)d_in[13];
    const float* W2  = (const float*)d_in[14];
    const float* b2  = (const float*)d_in[15];
    const float* l2g = (const float*)d_in[16];
    const float* l2b = (const float*)d_in[17];
    float* outp = (float*)d_out;

    const size_t NE  = (size_t)MROWS * Dm;    // 4194304
    const size_t WDD = (size_t)Dm * Dm;
    const size_t WDF = (size_t)Dm * DFFn;

    float* xbuf = (float*)d_ws;               // NE f32
    float* ybuf = xbuf + NE;                  // NE f32
    float* t2   = ybuf + NE;                  // NE f32 (LN input temp)
    f16* xh  = (f16*)(t2 + NE);               // NE
    f16* yh  = xh + NE;                       // NE
    f16* R   = yh + NE;                       // 4*NE f16 region
    f16* qh  = R;                             // q(=k) heads f16
    f16* vt  = R + 2 * NE;                    // v transposed per head (fused)
    f16* t1h = R + 3 * NE;                    // attention output f16
    f16* fbh = R;                             // FFN hidden (aliases R, 4*NE)
    f16* wkh = R + 4 * NE;                    // weights f16
    f16* wvh = wkh + 6 * WDD;
    f16* woh = wvh + 6 * WDD;
    f16* w1h = woh + 6 * WDD;                 // slots 0,1,3,5
    f16* w2h = w1h + 4 * WDF;

    // ---- per-call weight convert+transpose (f32 [K,N] -> f16 [N,K]) ----
    k_wconv<<<dim3(Dm / 32, Dm / 32, 6), 256, 0, stream>>>(Wk, wkh, Dm, Dm, 0);
    k_wconv<<<dim3(Dm / 32, Dm / 32, 6), 256, 0, stream>>>(Wv, wvh, Dm, Dm, 0);
    k_wconv<<<dim3(Dm / 32, Dm / 32, 6), 256, 0, stream>>>(Wo, woh, Dm, Dm, 0);
    k_wconv<<<dim3(DFFn / 32, Dm / 32, 4), 256, 0, stream>>>(W1, w1h, Dm, DFFn, 1);
    k_wconv<<<dim3(Dm / 32, DFFn / 32, 4), 256, 0, stream>>>(W2, w2h, DFFn, Dm, 1);

    const int n = (int)NE;
    k_copy2<<<n / 256, 256, 0, stream>>>(q_emb,  xbuf, xh, n);
    k_copy2<<<n / 256, 256, 0, stream>>>(qa_emb, ybuf, yh, n);

    // N=512 grids (256 blocks = 1 block/CU): BK=64. FFN1 (N=2048): BK=32.
    auto gemm16 = [&](const f16* A, const f16* Bt, const float* bias, f16* C,
                      int M, int N, int K) {
        k_gemm<0, 1, 0, 1><<<dim3(N / 128, M / 128), 256, 0, stream>>>(A, Bt, bias, nullptr, C, M, N, K);
    };
    auto gemm32 = [&](const f16* A, const f16* Bt, const float* bias, float* C,
                      int M, int N, int K) {
        k_gemm<0, 0, 0, 1><<<dim3(N / 128, M / 128), 256, 0, stream>>>(A, Bt, bias, C, nullptr, M, N, K);
    };
    auto gemmvt = [&](const f16* A, const f16* Bt, const float* bias, f16* C) {
        k_gemm<0, 1, 1, 1><<<dim3(Dm / 128, MROWS / 128), 256, 0, stream>>>(A, Bt, bias, nullptr, C, MROWS, Dm, Dm);
    };

    // finalOut: if non-null, the LAST LayerNorm's f32 result goes there
    // (the f32 residual stream is dead afterwards; f16 mirror still written).
    auto layer = [&](int l, int maskflag, float* Xq, f16* Xqh, f16* Xvh,
                     bool apply_pos, float* finalOut) {
        gemm16(Xqh, wkh + (size_t)l * WDD, bk + l * Dm, qh, MROWS, Dm, Dm);
        gemmvt(Xvh, wvh + (size_t)l * WDD, bv + l * Dm, vt);
        k_attn<<<Bsz * Hn * 32, 256, 0, stream>>>(qh, vt, t1h, gam + l * Hn, maskflag);
        gemm32(t1h, woh + (size_t)l * WDD, bo + l * Dm, t2, MROWS, Dm, Dm);
        if (apply_pos) {
            k_ln<<<MROWS / 4, 256, 0, stream>>>(t2, Xq, l1g + l * Dm, l1b + l * Dm, Xq, Xqh);
            int sl = (l < 2) ? l : ((l + 1) >> 1);
            k_gemm<1, 1, 0, 0><<<dim3(DFFn / 128, MROWS / 128), 256, 0, stream>>>(
                Xqh, w1h + (size_t)sl * WDF, b1 + l * DFFn, nullptr, fbh, MROWS, DFFn, Dm);
            k_gemm<0, 0, 0, 1><<<dim3(Dm / 128, MROWS / 128), 256, 0, stream>>>(
                fbh, w2h + (size_t)sl * WDF, b2 + l * Dm, t2, nullptr, MROWS, Dm, DFFn);
            k_ln<<<MROWS / 4, 256, 0, stream>>>(t2, Xq, l2g + l * Dm, l2b + l * Dm,
                                                finalOut ? finalOut : Xq, Xqh);
        } else {
            k_ln<<<MROWS / 4, 256, 0, stream>>>(t2, Xq, l1g + l * Dm, l1b + l * Dm,
                                                finalOut ? finalOut : Xq, Xqh);
        }
    };

    const size_t NEo = NE;
    // blocks_1: self-attn on y, mask=1, FFN. Layer 1 is y's final write -> out+NE.
    layer(0, 1, ybuf, yh, yh, true, nullptr);
    layer(1, 1, ybuf, yh, yh, true, outp + NEo);
    // blocks_2: (mask=1, no FFN) then (mask=0, values=y, FFN), twice.
    // Layer 5 is x's final write -> out.
    layer(2, 1, xbuf, xh, xh, false, nullptr);
    layer(3, 0, xbuf, xh, yh, true, nullptr);
    layer(4, 1, xbuf, xh, xh, false, nullptr);
    layer(5, 0, xbuf, xh, yh, true, outp);
}

// Round 6
// 1135.568 us; speedup vs baseline: 1.2298x; 1.0444x over previous
//
#include <hip/hip_runtime.h>
#include <hip/hip_bf16.h>

// Problem constants (AKT core): B=16, S=512, D=512, H=8, DFF=2048, NB=2, L=6
#define Bsz  16
#define Sl   512
#define Dm   512
#define Hn   8
#define DKh  64
#define DFFn 2048
#define MROWS (Bsz * Sl)      // 8192
#define NEGV (-1e32f)

typedef _Float16 f16;
typedef f16 f16x8 __attribute__((ext_vector_type(8)));
typedef f16 f16x4 __attribute__((ext_vector_type(4)));
typedef float f32x4 __attribute__((ext_vector_type(4)));

// async global->LDS, 16B per lane: lds dst = wave-uniform base + lane*16
#define GLDS16(g, l) __builtin_amdgcn_global_load_lds( \
    (const __attribute__((address_space(1))) void*)(g), \
    (__attribute__((address_space(3))) void*)(l), 16, 0, 0)

// ---------------------------------------------------------------------------
// copies
// ---------------------------------------------------------------------------
__global__ void k_copy2(const float* __restrict__ in, float* __restrict__ out,
                        f16* __restrict__ outh, int n) {
    int i = blockIdx.x * 256 + threadIdx.x;
    if (i < n) { float v = in[i]; out[i] = v; outh[i] = (f16)v; }
}

// bias concat: bkv[z][0:512) = bk[z], [512:1024) = bv[z]
__global__ void k_bcat(const float* __restrict__ bk, const float* __restrict__ bv,
                       float* __restrict__ bkv) {
    int i = blockIdx.x * 256 + threadIdx.x;   // 6*1024
    int z = i >> 10, c = i & 1023;
    bkv[i] = (c < 512) ? bk[z * 512 + c] : bv[z * 512 + c - 512];
}

// ---------------------------------------------------------------------------
// Weight convert+transpose: W[K,N] f32 -> Wt[N,K] f16, slice z at dst+z*zstride
// (zstride lets K- and V-weights interleave into one [1024][512] concat).
// lmap=1 maps output slot z -> source layer {0,1,3,5}.
// ---------------------------------------------------------------------------
__global__ __launch_bounds__(256) void k_wconv(const float* __restrict__ src,
        f16* __restrict__ dst, int K, int N, int lmap, size_t zstride)
{
    __shared__ float T[32][36];
    int z = blockIdx.z;
    int ls = lmap ? (z < 2 ? z : 2 * z - 1) : z;
    const float* S = src + (size_t)ls * K * N;
    f16* Dt = dst + (size_t)z * zstride;
    int n0 = blockIdx.x * 32, k0 = blockIdx.y * 32;
    int t = threadIdx.x;
    int r = t >> 3, c = (t & 7) * 4;
    float4 v = *(const float4*)(S + (size_t)(k0 + r) * N + n0 + c);
    T[r][c] = v.x; T[r][c + 1] = v.y; T[r][c + 2] = v.z; T[r][c + 3] = v.w;
    __syncthreads();
    int n = t >> 3, kq = (t & 7) * 4;
    f16x4 o = { (f16)T[kq][n], (f16)T[kq + 1][n], (f16)T[kq + 2][n], (f16)T[kq + 3][n] };
    *(f16x4*)(Dt + (size_t)(n0 + n) * K + k0 + kq) = o;
}

// ---------------------------------------------------------------------------
// MFMA f16 GEMM: C[M,N] = A[M,K] @ Bt[N,K]^T + bias[N]. A,Bt f16; bias f32.
// 128x128 tile, 4 waves, 16x16x32 MFMA, 4x4/wave. BK64: 64-wide K-step.
// 2-phase pipeline: stage(t+1) issued BEFORE compute(t), one barrier/step.
// VTOUT=1: write output in vt[bh][d][s] f16 layout (V-projection).
// VTOUT=2: fused KV (N=1024): n0<512 half -> Ch (qh, stride 512);
//          n0>=512 half -> vt layout via C-cast pointer.
// ---------------------------------------------------------------------------
template <int RELU, int OUT16, int VTOUT, int BK64>
__global__ __launch_bounds__(256) void k_gemm(
    const f16* __restrict__ A, const f16* __restrict__ Bt,
    const float* __restrict__ bias, float* __restrict__ C, f16* __restrict__ Ch,
    int M, int N, int K)
{
    constexpr int HL = BK64 ? 2 : 1;        // 32-wide halves per K-step
    constexpr int BUF = HL * 4096;          // f16 per buffer per matrix
    __shared__ f16 As[2 * BUF];
    __shared__ f16 Bs[2 * BUF];
    int tid = threadIdx.x;
    int w = tid >> 6, lane = tid & 63;
    int ln = lane & 15, rg = lane >> 4;
    int wr = w >> 1, wc = w & 1;
    int m0 = blockIdx.y * 128, n0 = blockIdx.x * 128;

    int s0 = tid, s1 = 256 + tid;
    int r0s = s0 >> 2, c0s = ((s0 & 3) ^ ((s0 >> 3) & 3));
    int r1s = s1 >> 2, c1s = ((s1 & 3) ^ ((s1 >> 3) & 3));

    const f16* a0 = A + (size_t)(m0 + r0s) * K + c0s * 8;
    const f16* a1 = A + (size_t)(m0 + r1s) * K + c1s * 8;
    const f16* b0 = Bt + (size_t)(n0 + r0s) * K + c0s * 8;
    const f16* b1 = Bt + (size_t)(n0 + r1s) * K + c1s * 8;

    int cc8 = (rg ^ ((ln >> 1) & 3)) * 8;

    f32x4 acc[4][4] = {};

    int nk = K >> (BK64 ? 6 : 5);

    auto STAGE = [&](int nb, int kt) {
        f16* lA = As + nb * BUF + w * 512;
        f16* lB = Bs + nb * BUF + w * 512;
        GLDS16(a0 + kt, lA);
        GLDS16(a1 + kt, lA + 2048);
        GLDS16(b0 + kt, lB);
        GLDS16(b1 + kt, lB + 2048);
        if (BK64) {
            GLDS16(a0 + kt + 32, lA + 4096);
            GLDS16(a1 + kt + 32, lA + 4096 + 2048);
            GLDS16(b0 + kt + 32, lB + 4096);
            GLDS16(b1 + kt + 32, lB + 4096 + 2048);
        }
    };

    STAGE(0, 0);
    __syncthreads();   // vmcnt(0) drain: buf0 ready

    int cur = 0;
    for (int t = 0; t < nk; ++t) {
        if (t + 1 < nk) STAGE(cur ^ 1, (t + 1) << (BK64 ? 6 : 5));

#pragma unroll
        for (int hh = 0; hh < HL; ++hh) {
            const f16* Ab = As + cur * BUF + hh * 4096;
            const f16* Bb = Bs + cur * BUF + hh * 4096;
            f16x8 af[4], bf[4];
#pragma unroll
            for (int i = 0; i < 4; ++i) {
                int m = wr * 64 + i * 16 + ln;
                af[i] = *(const f16x8*)(Ab + m * 32 + cc8);
                int nn = wc * 64 + i * 16 + ln;
                bf[i] = *(const f16x8*)(Bb + nn * 32 + cc8);
            }
#pragma unroll
            for (int i = 0; i < 4; ++i)
#pragma unroll
                for (int j = 0; j < 4; ++j)
                    acc[i][j] = __builtin_amdgcn_mfma_f32_16x16x32_f16(af[i], bf[j], acc[i][j], 0, 0, 0);
        }

        __syncthreads();   // drains vmcnt(0): next buffer staged, reads done
        cur ^= 1;
    }

#pragma unroll
    for (int j = 0; j < 4; ++j) {
        int col = n0 + wc * 64 + j * 16 + ln;
        float bj = bias[col];
#pragma unroll
        for (int i = 0; i < 4; ++i) {
            int rb = m0 + wr * 64 + i * 16 + rg * 4;
            if (VTOUT == 1) {
                // vt[((b*8+h)*64 + dk)*512 + s], s = 4 consecutive rows
                int bq = rb >> 9, s = rb & 511;
                int hh = col >> 6, dk = col & 63;
                f16x4 o;
#pragma unroll
                for (int r = 0; r < 4; ++r) o[r] = (f16)(acc[i][j][r] + bj);
                *(f16x4*)(Ch + (((size_t)(bq * 8 + hh) * 64 + dk) << 9) + s) = o;
            } else if (VTOUT == 2) {
                if (n0 < 512) {       // qh half (block-uniform branch)
#pragma unroll
                    for (int r = 0; r < 4; ++r)
                        Ch[(size_t)(rb + r) * 512 + col] = (f16)(acc[i][j][r] + bj);
                } else {              // vt half
                    f16* Cv = (f16*)C;
                    int colv = col - 512;
                    int bq = rb >> 9, s = rb & 511;
                    int hh = colv >> 6, dk = colv & 63;
                    f16x4 o;
#pragma unroll
                    for (int r = 0; r < 4; ++r) o[r] = (f16)(acc[i][j][r] + bj);
                    *(f16x4*)(Cv + (((size_t)(bq * 8 + hh) * 64 + dk) << 9) + s) = o;
                }
            } else {
#pragma unroll
                for (int r = 0; r < 4; ++r) {
                    float v = acc[i][j][r] + bj;
                    if (RELU) v = fmaxf(v, 0.f);
                    if (OUT16) Ch[(size_t)(rb + r) * N + col] = (f16)v;
                    else       C [(size_t)(rb + r) * N + col] = v;
                }
            }
        }
    }
}

// ---------------------------------------------------------------------------
// AKT attention body, specialized on JTC (valid 64-col j-tiles, 1..8).
// All trip counts / guards / jbase compile-time -> no per-element cmp/cndmask,
// no register spills (only pe2[4][JTC] persists; scores re-read from LDS and
// exp recomputed after the scan instead of caching score+cumsum arrays).
// ---------------------------------------------------------------------------
template <int JTC>
__device__ __forceinline__ void attn_body(
    float (*Sc)[516], f16* Ph, const f16* Qbase, const f16* vbase, f16* ob,
    f16x8 aq0, f16x8 aq1, float g,
    int w, int lane, int ln, int rg, int i0, int maskflag)
{
    // ---- Phase 1: scores, 16-col unit granularity across waves ----------
#pragma unroll
    for (int ui = 0; ui < JTC; ++ui) {
        int u = w + ui * 4;
        const f16* kb = Qbase + (size_t)(u * 16 + ln) * Dm + rg * 8;
        f16x8 b0 = *(const f16x8*)(kb);
        f16x8 b1 = *(const f16x8*)(kb + 32);
        f32x4 c = {};
        c = __builtin_amdgcn_mfma_f32_16x16x32_f16(aq0, b0, c, 0, 0, 0);
        c = __builtin_amdgcn_mfma_f32_16x16x32_f16(aq1, b1, c, 0, 0, 0);
#pragma unroll
        for (int r = 0; r < 4; ++r)
            Sc[rg * 4 + r][u * 16 + ln] = c[r];
    }
    __syncthreads();

    int jbase = lane * JTC;
    int im = i0 + w * 4;

    // ---- loop A: first-softmax partial sums (no storage) ----------------
    float run[4];
#pragma unroll
    for (int q = 0; q < 4; ++q) {
        int jmax = maskflag ? (im + q) : (im + q - 1);
        float acc = 0.f;
#pragma unroll
        for (int k = 0; k < JTC; ++k) {
            int j = jbase + k;
            float s = (j <= jmax) ? Sc[w * 4 + q][j] * 0.125f : NEGV;
            acc += __expf(s);              // exp(-1e32) = 0 for masked
        }
        run[q] = acc;
    }
    // 4 interleaved inclusive scans across lanes (j-ordered)
    float sl[4] = { run[0], run[1], run[2], run[3] };
#pragma unroll
    for (int off = 1; off < 64; off <<= 1) {
        float n0 = __shfl_up(sl[0], off);
        float n1 = __shfl_up(sl[1], off);
        float n2 = __shfl_up(sl[2], off);
        float n3 = __shfl_up(sl[3], off);
        if (lane >= off) { sl[0] += n0; sl[1] += n1; sl[2] += n2; sl[3] += n3; }
    }

    // ---- loop B: re-read scores, decay, second softmax (unnormalized) ---
    float pe2s[4][JTC];
    float Z2[4];
#pragma unroll
    for (int q = 0; q < 4; ++q) {
        float excl = sl[q] - run[q];
        float Z = __shfl(sl[q], 63);
        float inv = 1.f / Z;
        int i = im + q;
        int jmax = maskflag ? i : (i - 1);
        float csum = 0.f, z2 = 0.f;
#pragma unroll
        for (int k = 0; k < JTC; ++k) {
            int j = jbase + k;
            float s = (j <= jmax) ? Sc[w * 4 + q][j] * 0.125f : NEGV;
            float pe = __expf(s);
            csum += pe;                              // inclusive cumsum
            float rem = (Z - excl - csum) * inv;     // disttot - distcum
            float pos = fabsf((float)(i - j));
            float dd = fmaxf(rem * pos, 0.f);        // fmax(NaN,0)=0 safe
            float te = __expf(sqrtf(dd) * g);
            te = fminf(fmaxf(te, 1e-5f), 1e5f);
            float sc = (j <= jmax) ? s * te : NEGV;
            float pe2 = __expf(sc);                  // shift-free
            pe2s[q][k] = pe2;
            z2 += pe2;
        }
        Z2[q] = z2;
    }
    // 4 interleaved sum reductions
#pragma unroll
    for (int off = 32; off >= 1; off >>= 1) {
        Z2[0] += __shfl_xor(Z2[0], off);
        Z2[1] += __shfl_xor(Z2[1], off);
        Z2[2] += __shfl_xor(Z2[2], off);
        Z2[3] += __shfl_xor(Z2[3], off);
    }
    __syncthreads();   // ALL waves' Sc reads done; Ph may now overwrite Sc

    // ---- write normalized P f16 into swizzled Ph ------------------------
#pragma unroll
    for (int q = 0; q < 4; ++q) {
        int r = w * 4 + q;
        float inv2 = 1.f / Z2[q];
        int zp = (maskflag == 0) && (im + q == 0);
        if constexpr (JTC == 8) {
            int slot = (lane & ~7) | ((lane & 7) ^ (r & 7));
            f16x8 o8;
#pragma unroll
            for (int k = 0; k < 8; ++k)
                o8[k] = (f16)(zp ? 0.f : pe2s[q][k] * inv2);
            *(f16x8*)(Ph + r * 512 + slot * 8) = o8;
        } else if constexpr (JTC == 4) {
            int cj = lane >> 1;
            int slot = (cj & ~7) | ((cj & 7) ^ (r & 7));
            f16x4 o4;
#pragma unroll
            for (int k = 0; k < 4; ++k)
                o4[k] = (f16)(zp ? 0.f : pe2s[q][k] * inv2);
            *(f16x4*)(Ph + r * 512 + slot * 8 + (lane & 1) * 4) = o4;
        } else {
#pragma unroll
            for (int k = 0; k < JTC; ++k) {
                int j = jbase + k;
                int cj = j >> 3;
                int slot = (cj & ~7) | ((cj & 7) ^ (r & 7));
                Ph[r * 512 + slot * 8 + (j & 7)] =
                    (f16)(zp ? 0.f : pe2s[q][k] * inv2);
            }
        }
    }
    __syncthreads();

    // ---- Phase 3: O = P @ V, dual accumulator ---------------------------
    f32x4 oa0 = {}, oa1 = {};
#pragma unroll
    for (int f = 0; f < 2 * JTC; ++f) {
        f16x8 bv = *(const f16x8*)(vbase + (f >> 1) * 64 + (f & 1) * 32);
        int c = (f >> 1) * 8 + (f & 1) * 4 + rg;
        int slot = (c & ~7) | ((c & 7) ^ (ln & 7));
        f16x8 ap = *(const f16x8*)(Ph + ln * 512 + slot * 8);
        if (f & 1) oa1 = __builtin_amdgcn_mfma_f32_16x16x32_f16(ap, bv, oa1, 0, 0, 0);
        else       oa0 = __builtin_amdgcn_mfma_f32_16x16x32_f16(ap, bv, oa0, 0, 0, 0);
    }
    f32x4 oa = oa0 + oa1;
#pragma unroll
    for (int r = 0; r < 4; ++r)
        ob[(size_t)r * Dm] = (f16)oa[r];
}

// ---------------------------------------------------------------------------
// AKT attention. One block per (b, h, 16-row i-tile), 4 waves.
// XCD-chunked swizzle (proven: FETCH 61.5->8.3MB). Heavy-first LPT order.
// Body dispatched via block-uniform switch on jtc -> full specialization.
// ---------------------------------------------------------------------------
__global__ __launch_bounds__(256, 4) void k_attn(
    const f16* __restrict__ Qh, const f16* __restrict__ VT,
    f16* __restrict__ O, const float* __restrict__ gam, int maskflag)
{
    __shared__ float Sc[16][516];
    f16* Ph = (f16*)Sc;          // 16KB alias, safe after post-read barrier

    int tid = threadIdx.x;
    int w = tid >> 6, lane = tid & 63;
    int ln = lane & 15, rg = lane >> 4;

    // XCD-chunked bijective remap (4096 blocks, 8 XCDs, 512 each)
    int bid = blockIdx.x;
    int lbid = (bid & 7) * 512 + (bid >> 3);
    int tile = 31 - (lbid & 31);        // heavy-first within each bh
    int bh = lbid >> 5;
    int b = bh >> 3, h = bh & 7;
    int i0 = tile * 16;
    int jtc = (tile >> 2) + 1;          // valid j-tiles (64 cols each)

    const f16* Qbase = Qh + ((size_t)b * Sl) * Dm + h * DKh;
    const f16* vbase = VT + ((size_t)bh * 64 + w * 16 + ln) * 512 + rg * 8;
    f16* ob = O + ((size_t)b * Sl + i0 + rg * 4) * Dm + h * DKh + w * 16 + ln;

    float gm = gam[h];
    float g = -((gm > 20.f) ? gm : log1pf(__expf(gm)));   // -softplus(gamma)

    // A-frags: Q rows i0..i0+15, reused across units
    f16x8 aq0 = *(const f16x8*)(Qbase + (size_t)(i0 + ln) * Dm + rg * 8);
    f16x8 aq1 = *(const f16x8*)(Qbase + (size_t)(i0 + ln) * Dm + 32 + rg * 8);

    switch (jtc) {
    case 1: attn_body<1>(Sc, Ph, Qbase, vbase, ob, aq0, aq1, g, w, lane, ln, rg, i0, maskflag); break;
    case 2: attn_body<2>(Sc, Ph, Qbase, vbase, ob, aq0, aq1, g, w, lane, ln, rg, i0, maskflag); break;
    case 3: attn_body<3>(Sc, Ph, Qbase, vbase, ob, aq0, aq1, g, w, lane, ln, rg, i0, maskflag); break;
    case 4: attn_body<4>(Sc, Ph, Qbase, vbase, ob, aq0, aq1, g, w, lane, ln, rg, i0, maskflag); break;
    case 5: attn_body<5>(Sc, Ph, Qbase, vbase, ob, aq0, aq1, g, w, lane, ln, rg, i0, maskflag); break;
    case 6: attn_body<6>(Sc, Ph, Qbase, vbase, ob, aq0, aq1, g, w, lane, ln, rg, i0, maskflag); break;
    case 7: attn_body<7>(Sc, Ph, Qbase, vbase, ob, aq0, aq1, g, w, lane, ln, rg, i0, maskflag); break;
    default: attn_body<8>(Sc, Ph, Qbase, vbase, ob, aq0, aq1, g, w, lane, ln, rg, i0, maskflag); break;
    }
}

// ---------------------------------------------------------------------------
// Residual + LayerNorm: Out = LN(Xn + Rr)*g + b, dual f32+f16 output.
// Vectorized: float4 loads/stores (16B/lane), f16x4 half-store.
// ---------------------------------------------------------------------------
__global__ __launch_bounds__(256) void k_ln(
    const float* __restrict__ Xn, const float* __restrict__ Rr,
    const float* __restrict__ gw, const float* __restrict__ bw,
    float* __restrict__ Out, f16* __restrict__ Outh)
{
    int tid = threadIdx.x;
    int w = tid >> 6, lane = tid & 63;
    int row = blockIdx.x * 4 + w;
    const float* xr = Xn + (size_t)row * Dm;
    const float* rr = Rr + (size_t)row * Dm;
    int c0 = lane * 4, c1 = 256 + lane * 4;
    float4 va = *(const float4*)(xr + c0);
    float4 vb = *(const float4*)(xr + c1);
    float4 ra = *(const float4*)(rr + c0);
    float4 rb = *(const float4*)(rr + c1);
    va.x += ra.x; va.y += ra.y; va.z += ra.z; va.w += ra.w;
    vb.x += rb.x; vb.y += rb.y; vb.z += rb.z; vb.w += rb.w;
    float sum = va.x + va.y + va.z + va.w + vb.x + vb.y + vb.z + vb.w;
#pragma unroll
    for (int off = 32; off >= 1; off >>= 1) sum += __shfl_xor(sum, off);
    float mu = sum * (1.f / 512.f);
    float var = 0.f;
    {
        float d;
        d = va.x - mu; var += d * d;  d = va.y - mu; var += d * d;
        d = va.z - mu; var += d * d;  d = va.w - mu; var += d * d;
        d = vb.x - mu; var += d * d;  d = vb.y - mu; var += d * d;
        d = vb.z - mu; var += d * d;  d = vb.w - mu; var += d * d;
    }
#pragma unroll
    for (int off = 32; off >= 1; off >>= 1) var += __shfl_xor(var, off);
    float rs = rsqrtf(var * (1.f / 512.f) + 1e-5f);
    float4 ga = *(const float4*)(gw + c0);
    float4 gb = *(const float4*)(gw + c1);
    float4 ba = *(const float4*)(bw + c0);
    float4 bb = *(const float4*)(bw + c1);
    float4 oa, ob;
    oa.x = (va.x - mu) * rs * ga.x + ba.x;  oa.y = (va.y - mu) * rs * ga.y + ba.y;
    oa.z = (va.z - mu) * rs * ga.z + ba.z;  oa.w = (va.w - mu) * rs * ga.w + ba.w;
    ob.x = (vb.x - mu) * rs * gb.x + bb.x;  ob.y = (vb.y - mu) * rs * gb.y + bb.y;
    ob.z = (vb.z - mu) * rs * gb.z + bb.z;  ob.w = (vb.w - mu) * rs * gb.w + bb.w;
    float* orow = Out + (size_t)row * Dm;
    f16* ohrow = Outh + (size_t)row * Dm;
    *(float4*)(orow + c0) = oa;
    *(float4*)(orow + c1) = ob;
    f16x4 ha = { (f16)oa.x, (f16)oa.y, (f16)oa.z, (f16)oa.w };
    f16x4 hb = { (f16)ob.x, (f16)ob.y, (f16)ob.z, (f16)ob.w };
    *(f16x4*)(ohrow + c0) = ha;
    *(f16x4*)(ohrow + c1) = hb;
}

// ---------------------------------------------------------------------------
extern "C" void kernel_launch(void* const* d_in, const int* in_sizes, int n_in,
                              void* d_out, int out_size, void* d_ws, size_t ws_size,
                              hipStream_t stream)
{
    const float* q_emb  = (const float*)d_in[0];
    const float* qa_emb = (const float*)d_in[1];
    const float* Wk  = (const float*)d_in[3];
    const float* bk  = (const float*)d_in[4];
    const float* Wv  = (const float*)d_in[5];
    const float* bv  = (const float*)d_in[6];
    const float* Wo  = (const float*)d_in[7];
    const float* bo  = (const float*)d_in[8];
    const float* gam = (const float*)d_in[9];
    const float* l1g = (const float*)d_in[10];
    const float* l1b = (const float*)d_in[11];
    const float* W1  = (const float*)d_in[12];
    const float* b1  = (const float*)d_in[13];
    const float* W2  = (const float*)d_in[14];
    const float* b2  = (const float*)d_in[15];
    const float* l2g = (const float*)d_in[16];
    const float* l2b = (const float*)d_in[17];
    float* outp = (float*)d_out;

    const size_t NE  = (size_t)MROWS * Dm;    // 4194304
    const size_t WDD = (size_t)Dm * Dm;
    const size_t WDF = (size_t)Dm * DFFn;
    const size_t WKV = 2 * WDD;               // concat KV slice [1024][512]

    float* xbuf = (float*)d_ws;               // NE f32
    float* ybuf = xbuf + NE;                  // NE f32
    float* t2   = ybuf + NE;                  // NE f32 (LN input temp)
    f16* xh  = (f16*)(t2 + NE);               // NE
    f16* yh  = xh + NE;                       // NE
    f16* R   = yh + NE;                       // 4*NE f16 region
    f16* qh  = R;                             // q(=k) heads f16
    f16* vt  = R + 2 * NE;                    // v transposed per head (fused)
    f16* t1h = R + 3 * NE;                    // attention output f16
    f16* fbh = R;                             // FFN hidden (aliases R, 4*NE)
    f16* wkvh = R + 4 * NE;                   // concat KV weights [6][1024][512]
    f16* woh = wkvh + 6 * WKV;
    f16* w1h = woh + 6 * WDD;                 // slots 0,1,3,5
    f16* w2h = w1h + 4 * WDF;
    float* bkv = (float*)(w2h + 4 * WDF);     // [6][1024] f32

    // ---- per-call weight convert+transpose (f32 [K,N] -> f16 [N,K]) ----
    k_wconv<<<dim3(Dm / 32, Dm / 32, 6), 256, 0, stream>>>(Wk, wkvh, Dm, Dm, 0, WKV);
    k_wconv<<<dim3(Dm / 32, Dm / 32, 6), 256, 0, stream>>>(Wv, wkvh + WDD, Dm, Dm, 0, WKV);
    k_wconv<<<dim3(Dm / 32, Dm / 32, 6), 256, 0, stream>>>(Wo, woh, Dm, Dm, 0, WDD);
    k_wconv<<<dim3(DFFn / 32, Dm / 32, 4), 256, 0, stream>>>(W1, w1h, Dm, DFFn, 1, WDF);
    k_wconv<<<dim3(Dm / 32, DFFn / 32, 4), 256, 0, stream>>>(W2, w2h, DFFn, Dm, 1, WDF);
    k_bcat<<<24, 256, 0, stream>>>(bk, bv, bkv);

    const int n = (int)NE;
    k_copy2<<<n / 256, 256, 0, stream>>>(q_emb,  xbuf, xh, n);
    k_copy2<<<n / 256, 256, 0, stream>>>(qa_emb, ybuf, yh, n);

    auto gemm32 = [&](const f16* A, const f16* Bt, const float* bias, float* C,
                      int M, int N, int K) {
        k_gemm<0, 0, 0, 1><<<dim3(N / 128, M / 128), 256, 0, stream>>>(A, Bt, bias, C, nullptr, M, N, K);
    };

    // finalOut: if non-null, the LAST LayerNorm's f32 result goes there
    // (the f32 residual stream is dead afterwards; f16 mirror still written).
    auto layer = [&](int l, int maskflag, float* Xq, f16* Xqh, f16* Xvh,
                     bool apply_pos, float* finalOut) {
        if (Xqh == Xvh) {
            // fused KV projection: N=1024, 512 blocks (2/CU)
            k_gemm<0, 1, 2, 1><<<dim3(1024 / 128, MROWS / 128), 256, 0, stream>>>(
                Xqh, wkvh + (size_t)l * WKV, bkv + l * 1024, (float*)vt, qh, MROWS, 1024, Dm);
        } else {
            k_gemm<0, 1, 0, 1><<<dim3(Dm / 128, MROWS / 128), 256, 0, stream>>>(
                Xqh, wkvh + (size_t)l * WKV, bk + l * Dm, nullptr, qh, MROWS, Dm, Dm);
            k_gemm<0, 1, 1, 1><<<dim3(Dm / 128, MROWS / 128), 256, 0, stream>>>(
                Xvh, wkvh + (size_t)l * WKV + WDD, bv + l * Dm, nullptr, vt, MROWS, Dm, Dm);
        }
        k_attn<<<Bsz * Hn * 32, 256, 0, stream>>>(qh, vt, t1h, gam + l * Hn, maskflag);
        gemm32(t1h, woh + (size_t)l * WDD, bo + l * Dm, t2, MROWS, Dm, Dm);
        if (apply_pos) {
            k_ln<<<MROWS / 4, 256, 0, stream>>>(t2, Xq, l1g + l * Dm, l1b + l * Dm, Xq, Xqh);
            int sl = (l < 2) ? l : ((l + 1) >> 1);
            k_gemm<1, 1, 0, 0><<<dim3(DFFn / 128, MROWS / 128), 256, 0, stream>>>(
                Xqh, w1h + (size_t)sl * WDF, b1 + l * DFFn, nullptr, fbh, MROWS, DFFn, Dm);
            k_gemm<0, 0, 0, 1><<<dim3(Dm / 128, MROWS / 128), 256, 0, stream>>>(
                fbh, w2h + (size_t)sl * WDF, b2 + l * Dm, t2, nullptr, MROWS, Dm, DFFn);
            k_ln<<<MROWS / 4, 256, 0, stream>>>(t2, Xq, l2g + l * Dm, l2b + l * Dm,
                                                finalOut ? finalOut : Xq, Xqh);
        } else {
            k_ln<<<MROWS / 4, 256, 0, stream>>>(t2, Xq, l1g + l * Dm, l1b + l * Dm,
                                                finalOut ? finalOut : Xq, Xqh);
        }
    };

    const size_t NEo = NE;
    // blocks_1: self-attn on y, mask=1, FFN. Layer 1 is y's final write -> out+NE.
    layer(0, 1, ybuf, yh, yh, true, nullptr);
    layer(1, 1, ybuf, yh, yh, true, outp + NEo);
    // blocks_2: (mask=1, no FFN) then (mask=0, values=y, FFN), twice.
    // Layer 5 is x's final write -> out.
    layer(2, 1, xbuf, xh, xh, false, nullptr);
    layer(3, 0, xbuf, xh, yh, true, nullptr);
    layer(4, 1, xbuf, xh, xh, false, nullptr);
    layer(5, 0, xbuf, xh, yh, true, outp);
}

// Round 7
// 1106.430 us; speedup vs baseline: 1.2621x; 1.0263x over previous
//
#include <hip/hip_runtime.h>
#include <hip/hip_bf16.h>

// Problem constants (AKT core): B=16, S=512, D=512, H=8, DFF=2048, NB=2, L=6
#define Bsz  16
#define Sl   512
#define Dm   512
#define Hn   8
#define DKh  64
#define DFFn 2048
#define MROWS (Bsz * Sl)      // 8192
#define NEGV (-1e32f)

typedef _Float16 f16;
typedef f16 f16x8 __attribute__((ext_vector_type(8)));
typedef f16 f16x4 __attribute__((ext_vector_type(4)));
typedef float f32x4 __attribute__((ext_vector_type(4)));

// async global->LDS, 16B per lane: lds dst = wave-uniform base + lane*16
#define GLDS16(g, l) __builtin_amdgcn_global_load_lds( \
    (const __attribute__((address_space(1))) void*)(g), \
    (__attribute__((address_space(3))) void*)(l), 16, 0, 0)

// ---------------------------------------------------------------------------
// k_prep: all one-off preprocessing in ONE launch (fewer dispatch gaps).
// Flattened 1D grid segments:
//   [0,1536)      Wk  -> wkvh        (z-stride WKV)
//   [1536,3072)   Wv  -> wkvh+WDD    (z-stride WKV)
//   [3072,4608)   Wo  -> woh         (z-stride WDD)
//   [4608,8704)   W1  -> w1h  (lmap, 64x16 tiles, z-stride WDF)
//   [8704,12800)  W2  -> w2h  (lmap, 16x64 tiles, z-stride WDF)
//   [12800,12824) bias concat bk|bv -> bkv
//   [12824,29208) copy q_emb  -> xbuf + xh
//   [29208,45592) copy qa_emb -> ybuf + yh
// ---------------------------------------------------------------------------
struct PrepArgs {
    const float *Wk, *Wv, *Wo, *W1, *W2, *bk, *bv, *q_emb, *qa_emb;
    f16 *wkvh, *woh, *w1h, *w2h;
    float *bkv, *xbuf, *ybuf;
    f16 *xh, *yh;
};

__device__ __forceinline__ void wconv_body(const float* src, f16* dst,
        int K, int N, int lmap, size_t zstride, int z, int nx, int ny,
        int t, float (*T)[36])
{
    int ls = lmap ? (z < 2 ? z : 2 * z - 1) : z;
    const float* S = src + (size_t)ls * K * N;
    f16* Dt = dst + (size_t)z * zstride;
    int n0 = nx * 32, k0 = ny * 32;
    int r = t >> 3, c = (t & 7) * 4;
    float4 v = *(const float4*)(S + (size_t)(k0 + r) * N + n0 + c);
    T[r][c] = v.x; T[r][c + 1] = v.y; T[r][c + 2] = v.z; T[r][c + 3] = v.w;
    __syncthreads();
    int n = t >> 3, kq = (t & 7) * 4;
    f16x4 o = { (f16)T[kq][n], (f16)T[kq + 1][n], (f16)T[kq + 2][n], (f16)T[kq + 3][n] };
    *(f16x4*)(Dt + (size_t)(n0 + n) * K + k0 + kq) = o;
}

__global__ __launch_bounds__(256) void k_prep(PrepArgs a)
{
    __shared__ float T[32][36];
    int id = blockIdx.x;
    int t = threadIdx.x;
    const size_t WDD = (size_t)Dm * Dm;
    const size_t WDF = (size_t)Dm * DFFn;
    const size_t WKV = 2 * WDD;

    if (id < 4608) {
        int which = id / 1536, rest = id % 1536;
        int z = rest >> 8, r2 = rest & 255;
        int nx = r2 & 15, ny = r2 >> 4;
        if (which == 0)      wconv_body(a.Wk, a.wkvh,       Dm, Dm, 0, WKV, z, nx, ny, t, T);
        else if (which == 1) wconv_body(a.Wv, a.wkvh + WDD, Dm, Dm, 0, WKV, z, nx, ny, t, T);
        else                 wconv_body(a.Wo, a.woh,        Dm, Dm, 0, WDD, z, nx, ny, t, T);
    } else if (id < 8704) {
        int id2 = id - 4608;
        int z = id2 >> 10, r2 = id2 & 1023;
        int nx = r2 & 63, ny = r2 >> 6;          // N=2048: 64 x-tiles, 16 y
        wconv_body(a.W1, a.w1h, Dm, DFFn, 1, WDF, z, nx, ny, t, T);
    } else if (id < 12800) {
        int id3 = id - 8704;
        int z = id3 >> 10, r2 = id3 & 1023;
        int nx = r2 & 15, ny = r2 >> 4;          // K=2048: 16 x, 64 y
        wconv_body(a.W2, a.w2h, DFFn, Dm, 1, WDF, z, nx, ny, t, T);
    } else if (id < 12824) {
        int i = (id - 12800) * 256 + t;          // 6*1024
        int z = i >> 10, c = i & 1023;
        a.bkv[i] = (c < 512) ? a.bk[z * 512 + c] : a.bv[z * 512 + c - 512];
    } else if (id < 29208) {
        int i = (id - 12824) * 256 + t;
        float v = a.q_emb[i];
        a.xbuf[i] = v; a.xh[i] = (f16)v;
    } else {
        int i = (id - 29208) * 256 + t;
        float v = a.qa_emb[i];
        a.ybuf[i] = v; a.yh[i] = (f16)v;
    }
}

// ---------------------------------------------------------------------------
// MFMA f16 GEMM: C[M,N] = A[M,K] @ Bt[N,K]^T + bias[N]. A,Bt f16; bias f32.
// 128x128 tile, 4 waves, 16x16x32 MFMA, 4x4/wave. BK64: 64-wide K-step.
// 2-phase pipeline: stage(t+1) issued BEFORE compute(t), one barrier/step.
// VTOUT=1: write output in vt[bh][d][s] f16 layout (V-projection).
// VTOUT=2: fused KV (N=1024): n0<512 -> Ch (qh); n0>=512 -> vt via C-cast.
// VTOUT=3: DUAL independent projections in one launch (2 blocks/CU):
//          bx<4: A@Bt[0:512] -> qh;  bx>=4: A2@Bt[512:1024] -> vt (Ch2).
// ---------------------------------------------------------------------------
template <int RELU, int OUT16, int VTOUT, int BK64>
__global__ __launch_bounds__(256) void k_gemm(
    const f16* __restrict__ A, const f16* __restrict__ Bt,
    const float* __restrict__ bias, float* __restrict__ C, f16* __restrict__ Ch,
    int M, int N, int K,
    const f16* __restrict__ A2, f16* __restrict__ Ch2)
{
    constexpr int HL = BK64 ? 2 : 1;        // 32-wide halves per K-step
    constexpr int BUF = HL * 4096;          // f16 per buffer per matrix
    __shared__ f16 As[2 * BUF];
    __shared__ f16 Bs[2 * BUF];
    int tid = threadIdx.x;
    int w = tid >> 6, lane = tid & 63;
    int ln = lane & 15, rg = lane >> 4;
    int wr = w >> 1, wc = w & 1;
    int m0 = blockIdx.y * 128;
    int half = (VTOUT == 3) ? (blockIdx.x >> 2) : 0;
    int n0 = (VTOUT == 3) ? (blockIdx.x & 3) * 128 : blockIdx.x * 128;

    const f16* Ause = (VTOUT == 3 && half) ? A2 : A;
    const f16* Btuse = (VTOUT == 3) ? Bt + (size_t)half * 512 * 512 : Bt;
    const float* biasuse = (VTOUT == 3) ? bias + half * 512 : bias;

    int s0 = tid, s1 = 256 + tid;
    int r0s = s0 >> 2, c0s = ((s0 & 3) ^ ((s0 >> 3) & 3));
    int r1s = s1 >> 2, c1s = ((s1 & 3) ^ ((s1 >> 3) & 3));

    const f16* a0 = Ause + (size_t)(m0 + r0s) * K + c0s * 8;
    const f16* a1 = Ause + (size_t)(m0 + r1s) * K + c1s * 8;
    const f16* b0 = Btuse + (size_t)(n0 + r0s) * K + c0s * 8;
    const f16* b1 = Btuse + (size_t)(n0 + r1s) * K + c1s * 8;

    int cc8 = (rg ^ ((ln >> 1) & 3)) * 8;

    f32x4 acc[4][4] = {};

    int nk = K >> (BK64 ? 6 : 5);

    auto STAGE = [&](int nb, int kt) {
        f16* lA = As + nb * BUF + w * 512;
        f16* lB = Bs + nb * BUF + w * 512;
        GLDS16(a0 + kt, lA);
        GLDS16(a1 + kt, lA + 2048);
        GLDS16(b0 + kt, lB);
        GLDS16(b1 + kt, lB + 2048);
        if (BK64) {
            GLDS16(a0 + kt + 32, lA + 4096);
            GLDS16(a1 + kt + 32, lA + 4096 + 2048);
            GLDS16(b0 + kt + 32, lB + 4096);
            GLDS16(b1 + kt + 32, lB + 4096 + 2048);
        }
    };

    STAGE(0, 0);
    __syncthreads();   // vmcnt(0) drain: buf0 ready

    int cur = 0;
    for (int t = 0; t < nk; ++t) {
        if (t + 1 < nk) STAGE(cur ^ 1, (t + 1) << (BK64 ? 6 : 5));

#pragma unroll
        for (int hh = 0; hh < HL; ++hh) {
            const f16* Ab = As + cur * BUF + hh * 4096;
            const f16* Bb = Bs + cur * BUF + hh * 4096;
            f16x8 af[4], bf[4];
#pragma unroll
            for (int i = 0; i < 4; ++i) {
                int m = wr * 64 + i * 16 + ln;
                af[i] = *(const f16x8*)(Ab + m * 32 + cc8);
                int nn = wc * 64 + i * 16 + ln;
                bf[i] = *(const f16x8*)(Bb + nn * 32 + cc8);
            }
#pragma unroll
            for (int i = 0; i < 4; ++i)
#pragma unroll
                for (int j = 0; j < 4; ++j)
                    acc[i][j] = __builtin_amdgcn_mfma_f32_16x16x32_f16(af[i], bf[j], acc[i][j], 0, 0, 0);
        }

        __syncthreads();   // drains vmcnt(0): next buffer staged, reads done
        cur ^= 1;
    }

#pragma unroll
    for (int j = 0; j < 4; ++j) {
        int col = n0 + wc * 64 + j * 16 + ln;
        float bj = biasuse[col];
#pragma unroll
        for (int i = 0; i < 4; ++i) {
            int rb = m0 + wr * 64 + i * 16 + rg * 4;
            if (VTOUT == 1) {
                // vt[((b*8+h)*64 + dk)*512 + s], s = 4 consecutive rows
                int bq = rb >> 9, s = rb & 511;
                int hh = col >> 6, dk = col & 63;
                f16x4 o;
#pragma unroll
                for (int r = 0; r < 4; ++r) o[r] = (f16)(acc[i][j][r] + bj);
                *(f16x4*)(Ch + (((size_t)(bq * 8 + hh) * 64 + dk) << 9) + s) = o;
            } else if (VTOUT == 2) {
                if (n0 < 512) {       // qh half (block-uniform branch)
#pragma unroll
                    for (int r = 0; r < 4; ++r)
                        Ch[(size_t)(rb + r) * 512 + col] = (f16)(acc[i][j][r] + bj);
                } else {              // vt half
                    f16* Cv = (f16*)C;
                    int colv = col - 512;
                    int bq = rb >> 9, s = rb & 511;
                    int hh = colv >> 6, dk = colv & 63;
                    f16x4 o;
#pragma unroll
                    for (int r = 0; r < 4; ++r) o[r] = (f16)(acc[i][j][r] + bj);
                    *(f16x4*)(Cv + (((size_t)(bq * 8 + hh) * 64 + dk) << 9) + s) = o;
                }
            } else if (VTOUT == 3) {
                if (half == 0) {      // qh
#pragma unroll
                    for (int r = 0; r < 4; ++r)
                        Ch[(size_t)(rb + r) * 512 + col] = (f16)(acc[i][j][r] + bj);
                } else {              // vt
                    int bq = rb >> 9, s = rb & 511;
                    int hh = col >> 6, dk = col & 63;
                    f16x4 o;
#pragma unroll
                    for (int r = 0; r < 4; ++r) o[r] = (f16)(acc[i][j][r] + bj);
                    *(f16x4*)(Ch2 + (((size_t)(bq * 8 + hh) * 64 + dk) << 9) + s) = o;
                }
            } else {
#pragma unroll
                for (int r = 0; r < 4; ++r) {
                    float v = acc[i][j][r] + bj;
                    if (RELU) v = fmaxf(v, 0.f);
                    if (OUT16) Ch[(size_t)(rb + r) * N + col] = (f16)v;
                    else       C [(size_t)(rb + r) * N + col] = v;
                }
            }
        }
    }
}

// ---------------------------------------------------------------------------
// AKT attention body, specialized on JTC. Scores held in REGISTERS ss[4][JTC]
// after ONE vectorized LDS read (float4 b128, ~2-way bank alias vs 16-way
// scalar stride-8); loop B is LDS-free (recomputes cheap exps from ss).
// Masked lanes carry NEGV through s*te (|NEGV*te| <= 1e37 -> exp -> 0).
// ---------------------------------------------------------------------------
template <int JTC>
__device__ __forceinline__ void attn_body(
    float (*Sc)[516], f16* Ph, const f16* Qbase, const f16* vbase, f16* ob,
    f16x8 aq0, f16x8 aq1, float g,
    int w, int lane, int ln, int rg, int i0, int maskflag)
{
    // ---- Phase 1: scores, 16-col unit granularity across waves ----------
#pragma unroll
    for (int ui = 0; ui < JTC; ++ui) {
        int u = w + ui * 4;
        const f16* kb = Qbase + (size_t)(u * 16 + ln) * Dm + rg * 8;
        f16x8 b0 = *(const f16x8*)(kb);
        f16x8 b1 = *(const f16x8*)(kb + 32);
        f32x4 c = {};
        c = __builtin_amdgcn_mfma_f32_16x16x32_f16(aq0, b0, c, 0, 0, 0);
        c = __builtin_amdgcn_mfma_f32_16x16x32_f16(aq1, b1, c, 0, 0, 0);
#pragma unroll
        for (int r = 0; r < 4; ++r)
            Sc[rg * 4 + r][u * 16 + ln] = c[r];
    }
    __syncthreads();

    int jbase = lane * JTC;
    int im = i0 + w * 4;

    // ---- loop A: vector-read scores -> regs, mask+scale, first exp-sums -
    float ss[4][JTC];
    float run[4];
#pragma unroll
    for (int q = 0; q < 4; ++q) {
        const float* Srow = &Sc[w * 4 + q][0];
        if constexpr (JTC == 8) {
            float4 t0 = *(const float4*)(Srow + jbase);
            float4 t1 = *(const float4*)(Srow + jbase + 4);
            ss[q][0] = t0.x; ss[q][1] = t0.y; ss[q][2] = t0.z; ss[q][3] = t0.w;
            ss[q][4] = t1.x; ss[q][5] = t1.y; ss[q][6] = t1.z; ss[q][7] = t1.w;
        } else if constexpr (JTC == 4) {
            float4 t0 = *(const float4*)(Srow + jbase);
            ss[q][0] = t0.x; ss[q][1] = t0.y; ss[q][2] = t0.z; ss[q][3] = t0.w;
        } else {
#pragma unroll
            for (int k = 0; k < JTC; ++k) ss[q][k] = Srow[jbase + k];
        }
        int jmax = maskflag ? (im + q) : (im + q - 1);
        float acc = 0.f;
#pragma unroll
        for (int k = 0; k < JTC; ++k) {
            int j = jbase + k;
            float s = (j <= jmax) ? ss[q][k] * 0.125f : NEGV;
            ss[q][k] = s;
            acc += __expf(s);              // exp(-1e32) = 0 for masked
        }
        run[q] = acc;
    }
    // 4 interleaved inclusive scans across lanes (j-ordered)
    float sl[4] = { run[0], run[1], run[2], run[3] };
#pragma unroll
    for (int off = 1; off < 64; off <<= 1) {
        float n0 = __shfl_up(sl[0], off);
        float n1 = __shfl_up(sl[1], off);
        float n2 = __shfl_up(sl[2], off);
        float n3 = __shfl_up(sl[3], off);
        if (lane >= off) { sl[0] += n0; sl[1] += n1; sl[2] += n2; sl[3] += n3; }
    }

    // ---- loop B: LDS-free decay + second softmax (unnormalized) ---------
    float Z2[4];
#pragma unroll
    for (int q = 0; q < 4; ++q) {
        float excl = sl[q] - run[q];
        float Z = __shfl(sl[q], 63);
        float inv = 1.f / Z;
        int i = im + q;
        float csum = 0.f, z2 = 0.f;
#pragma unroll
        for (int k = 0; k < JTC; ++k) {
            int j = jbase + k;
            float s = ss[q][k];
            csum += __expf(s);                       // inclusive cumsum
            float rem = (Z - excl - csum) * inv;     // disttot - distcum
            float pos = fabsf((float)(i - j));
            float dd = fmaxf(rem * pos, 0.f);        // fmax(NaN,0)=0 safe
            float te = __expf(sqrtf(dd) * g);
            te = fminf(fmaxf(te, 1e-5f), 1e5f);
            float pe2 = __expf(s * te);              // masked: -1e32*te -> 0
            ss[q][k] = pe2;
            z2 += pe2;
        }
        Z2[q] = z2;
    }
    // 4 interleaved sum reductions
#pragma unroll
    for (int off = 32; off >= 1; off >>= 1) {
        Z2[0] += __shfl_xor(Z2[0], off);
        Z2[1] += __shfl_xor(Z2[1], off);
        Z2[2] += __shfl_xor(Z2[2], off);
        Z2[3] += __shfl_xor(Z2[3], off);
    }
    __syncthreads();   // ALL waves' Sc reads done; Ph may now overwrite Sc

    // ---- write normalized P f16 into swizzled Ph ------------------------
#pragma unroll
    for (int q = 0; q < 4; ++q) {
        int r = w * 4 + q;
        float inv2 = 1.f / Z2[q];
        int zp = (maskflag == 0) && (im + q == 0);
        if constexpr (JTC == 8) {
            int slot = (lane & ~7) | ((lane & 7) ^ (r & 7));
            f16x8 o8;
#pragma unroll
            for (int k = 0; k < 8; ++k)
                o8[k] = (f16)(zp ? 0.f : ss[q][k] * inv2);
            *(f16x8*)(Ph + r * 512 + slot * 8) = o8;
        } else if constexpr (JTC == 4) {
            int cj = lane >> 1;
            int slot = (cj & ~7) | ((cj & 7) ^ (r & 7));
            f16x4 o4;
#pragma unroll
            for (int k = 0; k < 4; ++k)
                o4[k] = (f16)(zp ? 0.f : ss[q][k] * inv2);
            *(f16x4*)(Ph + r * 512 + slot * 8 + (lane & 1) * 4) = o4;
        } else {
#pragma unroll
            for (int k = 0; k < JTC; ++k) {
                int j = jbase + k;
                int cj = j >> 3;
                int slot = (cj & ~7) | ((cj & 7) ^ (r & 7));
                Ph[r * 512 + slot * 8 + (j & 7)] =
                    (f16)(zp ? 0.f : ss[q][k] * inv2);
            }
        }
    }
    __syncthreads();

    // ---- Phase 3: O = P @ V, dual accumulator ---------------------------
    f32x4 oa0 = {}, oa1 = {};
#pragma unroll
    for (int f = 0; f < 2 * JTC; ++f) {
        f16x8 bv = *(const f16x8*)(vbase + (f >> 1) * 64 + (f & 1) * 32);
        int c = (f >> 1) * 8 + (f & 1) * 4 + rg;
        int slot = (c & ~7) | ((c & 7) ^ (ln & 7));
        f16x8 ap = *(const f16x8*)(Ph + ln * 512 + slot * 8);
        if (f & 1) oa1 = __builtin_amdgcn_mfma_f32_16x16x32_f16(ap, bv, oa1, 0, 0, 0);
        else       oa0 = __builtin_amdgcn_mfma_f32_16x16x32_f16(ap, bv, oa0, 0, 0, 0);
    }
    f32x4 oa = oa0 + oa1;
#pragma unroll
    for (int r = 0; r < 4; ++r)
        ob[(size_t)r * Dm] = (f16)oa[r];
}

// ---------------------------------------------------------------------------
// AKT attention. One block per (b, h, 16-row i-tile), 4 waves.
// XCD-chunked swizzle (proven: FETCH 61.5->8.3MB). Heavy-first LPT order.
// ---------------------------------------------------------------------------
__global__ __launch_bounds__(256, 4) void k_attn(
    const f16* __restrict__ Qh, const f16* __restrict__ VT,
    f16* __restrict__ O, const float* __restrict__ gam, int maskflag)
{
    __shared__ float Sc[16][516];
    f16* Ph = (f16*)Sc;          // 16KB alias, safe after post-read barrier

    int tid = threadIdx.x;
    int w = tid >> 6, lane = tid & 63;
    int ln = lane & 15, rg = lane >> 4;

    // XCD-chunked bijective remap (4096 blocks, 8 XCDs, 512 each)
    int bid = blockIdx.x;
    int lbid = (bid & 7) * 512 + (bid >> 3);
    int tile = 31 - (lbid & 31);        // heavy-first within each bh
    int bh = lbid >> 5;
    int b = bh >> 3, h = bh & 7;
    int i0 = tile * 16;
    int jtc = (tile >> 2) + 1;          // valid j-tiles (64 cols each)

    const f16* Qbase = Qh + ((size_t)b * Sl) * Dm + h * DKh;
    const f16* vbase = VT + ((size_t)bh * 64 + w * 16 + ln) * 512 + rg * 8;
    f16* ob = O + ((size_t)b * Sl + i0 + rg * 4) * Dm + h * DKh + w * 16 + ln;

    float gm = gam[h];
    float g = -((gm > 20.f) ? gm : log1pf(__expf(gm)));   // -softplus(gamma)

    // A-frags: Q rows i0..i0+15, reused across units
    f16x8 aq0 = *(const f16x8*)(Qbase + (size_t)(i0 + ln) * Dm + rg * 8);
    f16x8 aq1 = *(const f16x8*)(Qbase + (size_t)(i0 + ln) * Dm + 32 + rg * 8);

    switch (jtc) {
    case 1: attn_body<1>(Sc, Ph, Qbase, vbase, ob, aq0, aq1, g, w, lane, ln, rg, i0, maskflag); break;
    case 2: attn_body<2>(Sc, Ph, Qbase, vbase, ob, aq0, aq1, g, w, lane, ln, rg, i0, maskflag); break;
    case 3: attn_body<3>(Sc, Ph, Qbase, vbase, ob, aq0, aq1, g, w, lane, ln, rg, i0, maskflag); break;
    case 4: attn_body<4>(Sc, Ph, Qbase, vbase, ob, aq0, aq1, g, w, lane, ln, rg, i0, maskflag); break;
    case 5: attn_body<5>(Sc, Ph, Qbase, vbase, ob, aq0, aq1, g, w, lane, ln, rg, i0, maskflag); break;
    case 6: attn_body<6>(Sc, Ph, Qbase, vbase, ob, aq0, aq1, g, w, lane, ln, rg, i0, maskflag); break;
    case 7: attn_body<7>(Sc, Ph, Qbase, vbase, ob, aq0, aq1, g, w, lane, ln, rg, i0, maskflag); break;
    default: attn_body<8>(Sc, Ph, Qbase, vbase, ob, aq0, aq1, g, w, lane, ln, rg, i0, maskflag); break;
    }
}

// ---------------------------------------------------------------------------
// Residual + LayerNorm: Out = LN(Xn + Rr)*g + b, dual f32+f16 output.
// Vectorized: float4 loads/stores (16B/lane), f16x4 half-store.
// ---------------------------------------------------------------------------
__global__ __launch_bounds__(256) void k_ln(
    const float* __restrict__ Xn, const float* __restrict__ Rr,
    const float* __restrict__ gw, const float* __restrict__ bw,
    float* __restrict__ Out, f16* __restrict__ Outh)
{
    int tid = threadIdx.x;
    int w = tid >> 6, lane = tid & 63;
    int row = blockIdx.x * 4 + w;
    const float* xr = Xn + (size_t)row * Dm;
    const float* rr = Rr + (size_t)row * Dm;
    int c0 = lane * 4, c1 = 256 + lane * 4;
    float4 va = *(const float4*)(xr + c0);
    float4 vb = *(const float4*)(xr + c1);
    float4 ra = *(const float4*)(rr + c0);
    float4 rb = *(const float4*)(rr + c1);
    va.x += ra.x; va.y += ra.y; va.z += ra.z; va.w += ra.w;
    vb.x += rb.x; vb.y += rb.y; vb.z += rb.z; vb.w += rb.w;
    float sum = va.x + va.y + va.z + va.w + vb.x + vb.y + vb.z + vb.w;
#pragma unroll
    for (int off = 32; off >= 1; off >>= 1) sum += __shfl_xor(sum, off);
    float mu = sum * (1.f / 512.f);
    float var = 0.f;
    {
        float d;
        d = va.x - mu; var += d * d;  d = va.y - mu; var += d * d;
        d = va.z - mu; var += d * d;  d = va.w - mu; var += d * d;
        d = vb.x - mu; var += d * d;  d = vb.y - mu; var += d * d;
        d = vb.z - mu; var += d * d;  d = vb.w - mu; var += d * d;
    }
#pragma unroll
    for (int off = 32; off >= 1; off >>= 1) var += __shfl_xor(var, off);
    float rs = rsqrtf(var * (1.f / 512.f) + 1e-5f);
    float4 ga = *(const float4*)(gw + c0);
    float4 gb = *(const float4*)(gw + c1);
    float4 ba = *(const float4*)(bw + c0);
    float4 bb = *(const float4*)(bw + c1);
    float4 oa, ob;
    oa.x = (va.x - mu) * rs * ga.x + ba.x;  oa.y = (va.y - mu) * rs * ga.y + ba.y;
    oa.z = (va.z - mu) * rs * ga.z + ba.z;  oa.w = (va.w - mu) * rs * ga.w + ba.w;
    ob.x = (vb.x - mu) * rs * gb.x + bb.x;  ob.y = (vb.y - mu) * rs * gb.y + bb.y;
    ob.z = (vb.z - mu) * rs * gb.z + bb.z;  ob.w = (vb.w - mu) * rs * gb.w + bb.w;
    float* orow = Out + (size_t)row * Dm;
    f16* ohrow = Outh + (size_t)row * Dm;
    *(float4*)(orow + c0) = oa;
    *(float4*)(orow + c1) = ob;
    f16x4 ha = { (f16)oa.x, (f16)oa.y, (f16)oa.z, (f16)oa.w };
    f16x4 hb = { (f16)ob.x, (f16)ob.y, (f16)ob.z, (f16)ob.w };
    *(f16x4*)(ohrow + c0) = ha;
    *(f16x4*)(ohrow + c1) = hb;
}

// ---------------------------------------------------------------------------
extern "C" void kernel_launch(void* const* d_in, const int* in_sizes, int n_in,
                              void* d_out, int out_size, void* d_ws, size_t ws_size,
                              hipStream_t stream)
{
    const float* q_emb  = (const float*)d_in[0];
    const float* qa_emb = (const float*)d_in[1];
    const float* Wk  = (const float*)d_in[3];
    const float* bk  = (const float*)d_in[4];
    const float* Wv  = (const float*)d_in[5];
    const float* bv  = (const float*)d_in[6];
    const float* Wo  = (const float*)d_in[7];
    const float* bo  = (const float*)d_in[8];
    const float* gam = (const float*)d_in[9];
    const float* l1g = (const float*)d_in[10];
    const float* l1b = (const float*)d_in[11];
    const float* W1  = (const float*)d_in[12];
    const float* b1  = (const float*)d_in[13];
    const float* W2  = (const float*)d_in[14];
    const float* b2  = (const float*)d_in[15];
    const float* l2g = (const float*)d_in[16];
    const float* l2b = (const float*)d_in[17];
    float* outp = (float*)d_out;

    const size_t NE  = (size_t)MROWS * Dm;    // 4194304
    const size_t WDD = (size_t)Dm * Dm;
    const size_t WDF = (size_t)Dm * DFFn;
    const size_t WKV = 2 * WDD;               // concat KV slice [1024][512]

    float* xbuf = (float*)d_ws;               // NE f32
    float* ybuf = xbuf + NE;                  // NE f32
    float* t2   = ybuf + NE;                  // NE f32 (LN input temp)
    f16* xh  = (f16*)(t2 + NE);               // NE
    f16* yh  = xh + NE;                       // NE
    f16* R   = yh + NE;                       // 4*NE f16 region
    f16* qh  = R;                             // q(=k) heads f16
    f16* vt  = R + 2 * NE;                    // v transposed per head (fused)
    f16* t1h = R + 3 * NE;                    // attention output f16
    f16* fbh = R;                             // FFN hidden (aliases R, 4*NE)
    f16* wkvh = R + 4 * NE;                   // concat KV weights [6][1024][512]
    f16* woh = wkvh + 6 * WKV;
    f16* w1h = woh + 6 * WDD;                 // slots 0,1,3,5
    f16* w2h = w1h + 4 * WDF;
    float* bkv = (float*)(w2h + 4 * WDF);     // [6][1024] f32

    // ---- single prep launch: weight convert + bias concat + input copies
    PrepArgs pa;
    pa.Wk = Wk; pa.Wv = Wv; pa.Wo = Wo; pa.W1 = W1; pa.W2 = W2;
    pa.bk = bk; pa.bv = bv; pa.q_emb = q_emb; pa.qa_emb = qa_emb;
    pa.wkvh = wkvh; pa.woh = woh; pa.w1h = w1h; pa.w2h = w2h;
    pa.bkv = bkv; pa.xbuf = xbuf; pa.ybuf = ybuf; pa.xh = xh; pa.yh = yh;
    k_prep<<<45592, 256, 0, stream>>>(pa);

    // finalOut: if non-null, the LAST LayerNorm's f32 result goes there
    // (the f32 residual stream is dead afterwards; f16 mirror still written).
    auto layer = [&](int l, int maskflag, float* Xq, f16* Xqh, f16* Xvh,
                     bool apply_pos, float* finalOut) {
        if (Xqh == Xvh) {
            // fused KV projection: N=1024, 512 blocks (2/CU)
            k_gemm<0, 1, 2, 1><<<dim3(1024 / 128, MROWS / 128), 256, 0, stream>>>(
                Xqh, wkvh + (size_t)l * WKV, bkv + l * 1024, (float*)vt, qh,
                MROWS, 1024, Dm, nullptr, nullptr);
        } else {
            // DUAL: K-proj of Xqh and V-proj of Xvh in one 512-block launch
            k_gemm<0, 1, 3, 1><<<dim3(8, MROWS / 128), 256, 0, stream>>>(
                Xqh, wkvh + (size_t)l * WKV, bkv + l * 1024, nullptr, qh,
                MROWS, 512, Dm, Xvh, vt);
        }
        k_attn<<<Bsz * Hn * 32, 256, 0, stream>>>(qh, vt, t1h, gam + l * Hn, maskflag);
        k_gemm<0, 0, 0, 1><<<dim3(Dm / 128, MROWS / 128), 256, 0, stream>>>(
            t1h, woh + (size_t)l * WDD, bo + l * Dm, t2, nullptr,
            MROWS, Dm, Dm, nullptr, nullptr);
        if (apply_pos) {
            k_ln<<<MROWS / 4, 256, 0, stream>>>(t2, Xq, l1g + l * Dm, l1b + l * Dm, Xq, Xqh);
            int sl = (l < 2) ? l : ((l + 1) >> 1);
            k_gemm<1, 1, 0, 0><<<dim3(DFFn / 128, MROWS / 128), 256, 0, stream>>>(
                Xqh, w1h + (size_t)sl * WDF, b1 + l * DFFn, nullptr, fbh,
                MROWS, DFFn, Dm, nullptr, nullptr);
            k_gemm<0, 0, 0, 1><<<dim3(Dm / 128, MROWS / 128), 256, 0, stream>>>(
                fbh, w2h + (size_t)sl * WDF, b2 + l * Dm, t2, nullptr,
                MROWS, Dm, DFFn, nullptr, nullptr);
            k_ln<<<MROWS / 4, 256, 0, stream>>>(t2, Xq, l2g + l * Dm, l2b + l * Dm,
                                                finalOut ? finalOut : Xq, Xqh);
        } else {
            k_ln<<<MROWS / 4, 256, 0, stream>>>(t2, Xq, l1g + l * Dm, l1b + l * Dm,
                                                finalOut ? finalOut : Xq, Xqh);
        }
    };

    const size_t NEo = NE;
    // blocks_1: self-attn on y, mask=1, FFN. Layer 1 is y's final write -> out+NE.
    layer(0, 1, ybuf, yh, yh, true, nullptr);
    layer(1, 1, ybuf, yh, yh, true, outp + NEo);
    // blocks_2: (mask=1, no FFN) then (mask=0, values=y, FFN), twice.
    // Layer 5 is x's final write -> out.
    layer(2, 1, xbuf, xh, xh, false, nullptr);
    layer(3, 0, xbuf, xh, yh, true, nullptr);
    layer(4, 1, xbuf, xh, xh, false, nullptr);
    layer(5, 0, xbuf, xh, yh, true, outp);
}